// Round 23
// baseline (666.531 us; speedup 1.0000x reference)
//
#include <hip/hip_runtime.h>

#define HL 96
#define WL 96
#define HO 384
#define WO 384
#define NPIX (2*HO*WO)           // 294912 output pixels (B=2)
#define FEAT_ELEMS ((size_t)2*64*HL*WL)  // 1179648
#define PLANE (HL*WL)            // 9216
#define HG2 (NPIX/128)           // 2304 heavy blocks
#define LG2 (NPIX/64)            // 4608 light blocks

typedef unsigned short us4 __attribute__((ext_vector_type(4)));
typedef unsigned short us8 __attribute__((ext_vector_type(8)));
typedef __bf16         b8  __attribute__((ext_vector_type(8)));
typedef float          f32x4 __attribute__((ext_vector_type(4)));

__device__ __forceinline__ unsigned short f2b(float x) {
  unsigned u = __builtin_bit_cast(unsigned, x);
  unsigned r = (u + 0x7FFFu + ((u >> 16) & 1u)) >> 16;
  return (unsigned short)r;
}

__device__ __forceinline__ f32x4 MF(us8 a, us8 b, f32x4 c) {
  return __builtin_amdgcn_mfma_f32_16x16x32_bf16(
      __builtin_bit_cast(b8, a), __builtin_bit_cast(b8, b), c, 0, 0, 0);
}

// ---------------------------------------------------------------------------
// First conv (CIN=3): scalar-weight version — proven.
// ---------------------------------------------------------------------------
template<int CIN, int COPT, bool RELU, bool RES>
__global__ __launch_bounds__(256) void conv_s_k(
    const float* __restrict__ in, const float* __restrict__ wP,
    const float* __restrict__ bias, const float* __restrict__ res,
    float* __restrict__ out)
{
  const int t   = threadIdx.x;
  const int p   = blockIdx.x * 256 + t;
  const int co0 = blockIdx.y * COPT;
  const int b   = blockIdx.z;
  const int x   = p % WL;
  const bool xl = (x == 0), xr = (x == WL - 1);

  float acc[COPT];
  #pragma unroll
  for (int j = 0; j < COPT; ++j) acc[j] = bias[co0 + j];

  int  ic[3]; bool yv[3];
  int  im[3], ip[3];
  #pragma unroll
  for (int ky = 0; ky < 3; ++ky) {
    int pr = p + (ky - 1) * WL;
    yv[ky] = ((unsigned)pr < (unsigned)PLANE);
    ic[ky] = yv[ky] ? pr : 0;
    im[ky] = ic[ky] - 1; if (im[ky] < 0) im[ky] = 0;
    ip[ky] = ic[ky] + 1; if (ip[ky] > PLANE - 1) ip[ky] = PLANE - 1;
  }

  const float* inb = in + (size_t)b * CIN * PLANE;

  #pragma unroll 2
  for (int ci = 0; ci < CIN; ++ci) {
    const float* pl = inb + (size_t)ci * PLANE;
    #pragma unroll
    for (int ky = 0; ky < 3; ++ky) {
      float am = pl[im[ky]];
      float a0 = pl[ic[ky]];
      float ap = pl[ip[ky]];
      if (!yv[ky]) { am = 0.f; a0 = 0.f; ap = 0.f; }
      if (xl) am = 0.f;
      if (xr) ap = 0.f;
      const float* wrow = wP + (size_t)(ci * 9 + ky * 3) * 64 + co0;
      #pragma unroll
      for (int j = 0; j < COPT; ++j) acc[j] += am * wrow[j];
      #pragma unroll
      for (int j = 0; j < COPT; ++j) acc[j] += a0 * wrow[64 + j];
      #pragma unroll
      for (int j = 0; j < COPT; ++j) acc[j] += ap * wrow[128 + j];
    }
  }

  size_t ob = ((size_t)b * 64 + co0) * PLANE + p;
  #pragma unroll
  for (int j = 0; j < COPT; ++j) {
    float v = acc[j];
    if (RELU) v = fmaxf(v, 0.f);
    if (RES)  v += res[ob + (size_t)j * PLANE];
    out[ob + (size_t)j * PLANE] = v;
  }
}

// ---------------------------------------------------------------------------
// Residual conv (CIN=64): LDS-staged weights (r15-measured best).
// ---------------------------------------------------------------------------
template<bool RELU, bool RES>
__global__ __launch_bounds__(256) void conv_lw_k(
    const float* __restrict__ in, const float* __restrict__ wG,
    const float* __restrict__ bias, const float* __restrict__ res,
    float* __restrict__ out)
{
  __shared__ float sw[576 * 4];

  const int t   = threadIdx.x;
  const int p   = blockIdx.x * 256 + t;
  const int co0 = blockIdx.y * 4;
  const int b   = blockIdx.z;
  const int x   = p % WL;
  const bool xl = (x == 0), xr = (x == WL - 1);

  {
    const float4* s4 = (const float4*)(wG + (size_t)blockIdx.y * 2304);
    float4* d4 = (float4*)sw;
    for (int i = t; i < 576; i += 256) d4[i] = s4[i];
  }

  float acc[4];
  #pragma unroll
  for (int j = 0; j < 4; ++j) acc[j] = bias[co0 + j];

  int  ic[3]; bool yv[3];
  int  im[3], ip[3];
  #pragma unroll
  for (int ky = 0; ky < 3; ++ky) {
    int pr = p + (ky - 1) * WL;
    yv[ky] = ((unsigned)pr < (unsigned)PLANE);
    ic[ky] = yv[ky] ? pr : 0;
    im[ky] = ic[ky] - 1; if (im[ky] < 0) im[ky] = 0;
    ip[ky] = ic[ky] + 1; if (ip[ky] > PLANE - 1) ip[ky] = PLANE - 1;
  }

  const float* inb = in + (size_t)b * 64 * PLANE;
  __syncthreads();

  #pragma unroll 2
  for (int ci = 0; ci < 64; ++ci) {
    const float* pl = inb + (size_t)ci * PLANE;
    #pragma unroll
    for (int ky = 0; ky < 3; ++ky) {
      float am = pl[im[ky]];
      float a0 = pl[ic[ky]];
      float ap = pl[ip[ky]];
      if (!yv[ky]) { am = 0.f; a0 = 0.f; ap = 0.f; }
      if (xl) am = 0.f;
      if (xr) ap = 0.f;
      const float* wrow = &sw[(ci * 9 + ky * 3) * 4];
      #pragma unroll
      for (int j = 0; j < 4; ++j) acc[j] += am * wrow[j];
      #pragma unroll
      for (int j = 0; j < 4; ++j) acc[j] += a0 * wrow[4 + j];
      #pragma unroll
      for (int j = 0; j < 4; ++j) acc[j] += ap * wrow[8 + j];
    }
  }

  size_t ob = ((size_t)b * 64 + co0) * PLANE + p;
  #pragma unroll
  for (int j = 0; j < 4; ++j) {
    float v = acc[j];
    if (RELU) v = fmaxf(v, 0.f);
    if (RES)  v += res[ob + (size_t)j * PLANE];
    out[ob + (size_t)j * PLANE] = v;
  }
}

// ---------------------------------------------------------------------------
// ONE fused prep kernel
// ---------------------------------------------------------------------------
__device__ __forceinline__ void prep_bf16(const float* __restrict__ src,
    unsigned short* __restrict__ dst, int K, int N, int Kp, int i)
{
  int n = i / Kp, k = i - n * Kp;
  float v = (k < K && n < N) ? src[(size_t)k * N + n] : 0.f;
  dst[i] = f2b(v);
}
__device__ __forceinline__ void prep_conv(const float* __restrict__ src,
    float* __restrict__ dst, int cin, int i)
{
  int co = i % 64; int r = i / 64;
  int ci = r / 9, tap = r % 9;
  dst[i] = src[((size_t)co * cin + ci) * 9 + tap];
}
// co-grouped layout for conv_lw_k
__device__ __forceinline__ void prep_conv2(const float* __restrict__ src,
    float* __restrict__ dst, int i)
{
  int j  = i & 3;
  int t2 = i >> 2;
  int cg = t2 / 576;
  int r  = t2 - cg * 576;
  int ci = r / 9, tap = r - ci * 9;
  int co = cg * 4 + j;
  dst[i] = src[((size_t)co * 64 + ci) * 9 + tap];
}

#define PREP_TOTAL 467648
__global__ __launch_bounds__(256) void prep_all_k(
    const float* __restrict__ lw1, const float* __restrict__ lw2,
    const float* __restrict__ lw3, const float* __restrict__ hw1,
    const float* __restrict__ hmw, const float* __restrict__ hwo,
    const float* __restrict__ enc_w_in, const float* __restrict__ enc_rw,
    unsigned short* __restrict__ lw1T, unsigned short* __restrict__ lw2T,
    unsigned short* __restrict__ lw3T, unsigned short* __restrict__ hw1T,
    unsigned short* __restrict__ hm0T, unsigned short* __restrict__ hm1T,
    unsigned short* __restrict__ hwoT, float* __restrict__ cwIn,
    float* __restrict__ cwRes)
{
  int i = blockIdx.x * 256 + threadIdx.x;
  if (i >= PREP_TOTAL) return;
  if (i < 6144)  { prep_bf16(lw1, lw1T, 68, 64, 96, i);    return; } i -= 6144;
  if (i < 4096)  { prep_bf16(lw2, lw2T, 64, 64, 64, i);    return; } i -= 4096;
  if (i < 1024)  { prep_bf16(lw3, lw3T, 64, 3, 64, i);     return; } i -= 1024;
  if (i < 24576) { prep_bf16(hw1, hw1T, 68, 256, 96, i);   return; } i -= 24576;
  if (i < 65536) { prep_bf16(hmw, hm0T, 256, 256, 256, i); return; } i -= 65536;
  if (i < 65536) { prep_bf16(hmw + 65536, hm1T, 256, 256, 256, i); return; } i -= 65536;
  if (i < 4096)  { prep_bf16(hwo, hwoT, 256, 3, 256, i);   return; } i -= 4096;
  if (i < 1728)  { prep_conv(enc_w_in, cwIn, 3, i);        return; } i -= 1728;
  int l = i / 36864, r = i % 36864;
  prep_conv2(enc_rw + (size_t)l * 36864, cwRes + (size_t)l * 36864, r);
}

__global__ __launch_bounds__(256) void nchw_to_nhwc_k(const float* __restrict__ in,
                                                      float* __restrict__ out)
{
  __shared__ float s[64][65];
  const int b = blockIdx.y;
  const int pix0 = blockIdx.x * 64;
  const int t = threadIdx.x;
  #pragma unroll
  for (int cc = 0; cc < 16; ++cc) {
    int co = cc * 4 + (t >> 6);
    int px = t & 63;
    s[px][co] = in[((size_t)b * 64 + co) * PLANE + pix0 + px];
  }
  __syncthreads();
  #pragma unroll
  for (int pp = 0; pp < 16; ++pp) {
    int px = pp * 4 + (t >> 6);
    int co = t & 63;
    out[((size_t)b * PLANE + pix0 + px) * 64 + co] = s[px][co];
  }
}

// ---------------------------------------------------------------------------
// MFMA helpers, parametrized on MT (m-tiles per wave)
// ---------------------------------------------------------------------------
template<int NT, int KT, int MT>
__device__ __forceinline__ void mfma_compute(
    const unsigned short* __restrict__ aBase, int AS,
    const unsigned short* __restrict__ WT, int Kpad,
    int n0, int lane, f32x4 (&acc)[MT][NT])
{
  const int lr = lane & 15;
  const int lc = lane >> 4;
  #pragma unroll
  for (int m = 0; m < MT; ++m)
    #pragma unroll
    for (int j = 0; j < NT; ++j) acc[m][j] = (f32x4){0.f, 0.f, 0.f, 0.f};

  const unsigned short* aP = aBase + lr * AS + lc * 8;
  const unsigned short* bP = WT + (size_t)(n0 + lr) * Kpad + lc * 8;

  constexpr int KCH = (KT >= 4) ? 4 : KT;
  #pragma unroll
  for (int kc = 0; kc < KT; kc += KCH) {
    us8 breg[KCH][NT];
    #pragma unroll
    for (int kk = 0; kk < KCH; ++kk)
      #pragma unroll
      for (int j = 0; j < NT; ++j)
        breg[kk][j] = *(const us8*)(bP + (size_t)j * 16 * Kpad + (kc + kk) * 32);
    #pragma unroll
    for (int kc2 = 0; kc2 < KCH; ++kc2) {
      us8 a0[MT];
      #pragma unroll
      for (int m = 0; m < MT; ++m)
        a0[m] = *(const us8*)(aP + (m * 16) * AS + (kc + kc2) * 32);
      #pragma unroll
      for (int m = 0; m < MT; ++m)
        #pragma unroll
        for (int j = 0; j < NT; ++j)
          acc[m][j] = MF(a0[m], breg[kc2][j], acc[m][j]);
    }
  }
}

template<int NT, bool RELU, int MT>
__device__ __forceinline__ void mfma_store(
    const f32x4 (&acc)[MT][NT], const float* __restrict__ bias,
    unsigned short* __restrict__ dBase, int DS, int dCol0, int n0, int lane)
{
  const int lr = lane & 15;
  const int lc = lane >> 4;
  #pragma unroll
  for (int j = 0; j < NT; ++j) {
    int n = n0 + j * 16 + lr;
    float bv = bias[n];
    #pragma unroll
    for (int m = 0; m < MT; ++m)
      #pragma unroll
      for (int r = 0; r < 4; ++r) {
        float v = acc[m][j][r] + bv;
        if (RELU) v = fmaxf(v, 0.f);
        dBase[(m * 16 + lc * 4 + r) * DS + dCol0 + n] = f2b(v);
      }
  }
}

template<int KT>
__device__ __forceinline__ void mfma_out3w(
    const unsigned short* __restrict__ aBase, int AS,
    const unsigned short* __restrict__ WT, int Kpad,
    const float* __restrict__ bias, float (*dst)[4], int mtile, int lane)
{
  const int lr = lane & 15;
  const int lc = lane >> 4;
  f32x4 acc = (f32x4){0.f, 0.f, 0.f, 0.f};
  const unsigned short* aP = aBase + (mtile * 16 + lr) * AS + lc * 8;
  const unsigned short* bP = WT + (size_t)lr * Kpad + lc * 8;

  constexpr int KCH = (KT >= 4) ? 4 : KT;
  #pragma unroll
  for (int kc = 0; kc < KT; kc += KCH) {
    us8 breg[KCH];
    #pragma unroll
    for (int kk = 0; kk < KCH; ++kk)
      breg[kk] = *(const us8*)(bP + (kc + kk) * 32);
    #pragma unroll
    for (int kk = 0; kk < KCH; ++kk) {
      us8 a = *(const us8*)(aP + (kc + kk) * 32);
      acc = MF(a, breg[kk], acc);
    }
  }
  if (lr < 3) {
    float bv = bias[lr];
    #pragma unroll
    for (int r = 0; r < 4; ++r)
      dst[mtile * 16 + lc * 4 + r][lr] = acc[r] + bv;
  }
}

// ---------------------------------------------------------------------------
// Shared helpers
// ---------------------------------------------------------------------------
__device__ __forceinline__ void nearest_idx(float gy, float gx, int& iy, int& ix)
{
  float fy = (gy + 1.f) * (HL * 0.5f) - 0.5f;
  float fx = (gx + 1.f) * (WL * 0.5f) - 0.5f;
  iy = min(max((int)floorf(fy + 0.5f), 0), HL - 1);
  ix = min(max((int)floorf(fx + 0.5f), 0), WL - 1);
}

__device__ __forceinline__ float bilinear_lr(const float* __restrict__ lrimg,
                                             int b, int ch, float gy, float gx)
{
  float x = (gx + 1.f) * (WL * 0.5f) - 0.5f;
  float y = (gy + 1.f) * (HL * 0.5f) - 0.5f;
  float xf = floorf(x), yf = floorf(y);
  float wx = x - xf, wy = y - yf;
  int x0i = min(max((int)xf,     0), WL - 1);
  int x1i = min(max((int)xf + 1, 0), WL - 1);
  int y0i = min(max((int)yf,     0), HL - 1);
  int y1i = min(max((int)yf + 1, 0), HL - 1);
  const float* img = lrimg + ((size_t)b * 3 + ch) * PLANE;
  float v00 = img[y0i * WL + x0i], v01 = img[y0i * WL + x1i];
  float v10 = img[y1i * WL + x0i], v11 = img[y1i * WL + x1i];
  return v00 * (1.f - wx) * (1.f - wy) + v01 * wx * (1.f - wy)
       + v10 * (1.f - wx) * wy + v11 * wx * wy;
}

// ---------------------------------------------------------------------------
// Pass 1 (v7): scalar-weight classifier, 4 px/thread, JB=16 (j0=0,16,32,48).
// Four FMA chains share each wave-uniform weight s_load; total K$ weight
// traffic halves vs 2px. Per-pixel FP order identical to r14/r22 (each
// acc[j] = bias + k-ascending; logits accumulate j-ascending).
// ---------------------------------------------------------------------------
template<int JB>
__device__ __forceinline__ void cls_block4(
    const float* __restrict__ fpA, const float* __restrict__ fpB,
    const float* __restrict__ fpC, const float* __restrict__ fpD,
    const float4& eA, const float4& eB, const float4& eC, const float4& eD,
    const float* __restrict__ cw1, const float* __restrict__ cb1,
    const float* __restrict__ cw2, int j0,
    float& l0a, float& l1a, float& l0b, float& l1b,
    float& l0c, float& l1c, float& l0d, float& l1d)
{
  float accA[JB], accB[JB], accC[JB], accD[JB];
  #pragma unroll
  for (int j = 0; j < JB; ++j) {
    float bv = cb1[j0 + j];
    accA[j] = bv; accB[j] = bv; accC[j] = bv; accD[j] = bv;
  }
  #pragma unroll 4
  for (int kq = 0; kq < 16; ++kq) {
    float4 a4A = *(const float4*)(fpA + kq * 4);
    float4 a4B = *(const float4*)(fpB + kq * 4);
    float4 a4C = *(const float4*)(fpC + kq * 4);
    float4 a4D = *(const float4*)(fpD + kq * 4);
    float avA[4] = {a4A.x, a4A.y, a4A.z, a4A.w};
    float avB[4] = {a4B.x, a4B.y, a4B.z, a4B.w};
    float avC[4] = {a4C.x, a4C.y, a4C.z, a4C.w};
    float avD[4] = {a4D.x, a4D.y, a4D.z, a4D.w};
    #pragma unroll
    for (int kk = 0; kk < 4; ++kk) {
      const float* wr = cw1 + (size_t)(kq * 4 + kk) * 64 + j0;
      float aA = avA[kk], aB = avB[kk], aC = avC[kk], aD = avD[kk];
      #pragma unroll
      for (int j = 0; j < JB; ++j) {
        float w = wr[j];
        accA[j] += aA * w; accB[j] += aB * w;
        accC[j] += aC * w; accD[j] += aD * w;
      }
    }
  }
  {
    const float* wr = cw1 + (size_t)64 * 64 + j0;
    #pragma unroll
    for (int j = 0; j < JB; ++j) {
      float w = wr[j];
      accA[j] += eA.x * w; accB[j] += eB.x * w;
      accC[j] += eC.x * w; accD[j] += eD.x * w;
    }
    wr += 64;
    #pragma unroll
    for (int j = 0; j < JB; ++j) {
      float w = wr[j];
      accA[j] += eA.y * w; accB[j] += eB.y * w;
      accC[j] += eC.y * w; accD[j] += eD.y * w;
    }
    wr += 64;
    #pragma unroll
    for (int j = 0; j < JB; ++j) {
      float w = wr[j];
      accA[j] += eA.z * w; accB[j] += eB.z * w;
      accC[j] += eC.z * w; accD[j] += eD.z * w;
    }
    wr += 64;
    #pragma unroll
    for (int j = 0; j < JB; ++j) {
      float w = wr[j];
      accA[j] += eA.w * w; accB[j] += eB.w * w;
      accC[j] += eC.w * w; accD[j] += eD.w * w;
    }
  }
  #pragma unroll
  for (int j = 0; j < JB; ++j) {
    float hA = fmaxf(accA[j], 0.f);
    float hB = fmaxf(accB[j], 0.f);
    float hC = fmaxf(accC[j], 0.f);
    float hD = fmaxf(accD[j], 0.f);
    float w0 = cw2[(j0 + j) * 2 + 0], w1 = cw2[(j0 + j) * 2 + 1];
    l0a += hA * w0; l1a += hA * w1;
    l0b += hB * w0; l1b += hB * w1;
    l0c += hC * w0; l1c += hC * w1;
    l0d += hD * w0; l1d += hD * w1;
  }
}

__device__ __forceinline__ void cls_setup_px(
    const float* __restrict__ featT, const float* __restrict__ coord,
    const float* __restrict__ cell, int g, const float*& fp, float4& e)
{
  int b = g / (HO * WO);
  float gy = coord[(size_t)g * 2 + 0];
  float gx = coord[(size_t)g * 2 + 1];
  int iy, ix; nearest_idx(gy, gx, iy, ix);
  fp = featT + (((size_t)b * PLANE) + iy * WL + ix) * 64;
  float cy = (2.f * iy + 1.f) / HL - 1.f;
  float cx = (2.f * ix + 1.f) / WL - 1.f;
  e.x = (gy - cy) * HL; e.y = (gx - cx) * WL;
  e.z = cell[(size_t)g * 2 + 0] * HL;
  e.w = cell[(size_t)g * 2 + 1] * WL;
}

__global__ __launch_bounds__(256, 4) void cls_gate4_k(
    const float* __restrict__ featT, const float* __restrict__ coord,
    const float* __restrict__ cell,
    const float* __restrict__ cw1, const float* __restrict__ cb1,
    const float* __restrict__ cw2, const float* __restrict__ cb2,
    int* __restrict__ counters, unsigned* __restrict__ easyList,
    unsigned* __restrict__ hardList)
{
  const int T  = blockIdx.x * 256 + threadIdx.x;
  const int gA = T * 4, gB = gA + 1, gC = gA + 2, gD = gA + 3;

  const float *fpA, *fpB, *fpC, *fpD;
  float4 eA, eB, eC, eD;
  cls_setup_px(featT, coord, cell, gA, fpA, eA);
  cls_setup_px(featT, coord, cell, gB, fpB, eB);
  cls_setup_px(featT, coord, cell, gC, fpC, eC);
  cls_setup_px(featT, coord, cell, gD, fpD, eD);

  float l0a = cb2[0], l1a = cb2[1];
  float l0b = cb2[0], l1b = cb2[1];
  float l0c = cb2[0], l1c = cb2[1];
  float l0d = cb2[0], l1d = cb2[1];
  cls_block4<16>(fpA, fpB, fpC, fpD, eA, eB, eC, eD, cw1, cb1, cw2, 0,
                 l0a, l1a, l0b, l1b, l0c, l1c, l0d, l1d);
  cls_block4<16>(fpA, fpB, fpC, fpD, eA, eB, eC, eD, cw1, cb1, cw2, 16,
                 l0a, l1a, l0b, l1b, l0c, l1c, l0d, l1d);
  cls_block4<16>(fpA, fpB, fpC, fpD, eA, eB, eC, eD, cw1, cb1, cw2, 32,
                 l0a, l1a, l0b, l1b, l0c, l1c, l0d, l1d);
  cls_block4<16>(fpA, fpB, fpC, fpD, eA, eB, eC, eD, cw1, cb1, cw2, 48,
                 l0a, l1a, l0b, l1b, l0c, l1c, l0d, l1d);
  bool hardA = (l1a > l0a);
  bool hardB = (l1b > l0b);
  bool hardC = (l1c > l0c);
  bool hardD = (l1d > l0d);

  unsigned long long mh0 = __ballot(hardA);
  unsigned long long mh1 = __ballot(hardB);
  unsigned long long mh2 = __ballot(hardC);
  unsigned long long mh3 = __ballot(hardD);
  int lane = threadIdx.x & 63;
  int nh0 = __popcll(mh0), nh1 = __popcll(mh1);
  int nh2 = __popcll(mh2), nh3 = __popcll(mh3);
  int nh = nh0 + nh1 + nh2 + nh3;
  int baseH = 0, baseE = 0;
  if (lane == 0) {
    baseH = atomicAdd(&counters[1], nh);
    baseE = atomicAdd(&counters[0], 256 - nh);
  }
  baseH = __shfl(baseH, 0);
  baseE = __shfl(baseE, 0);
  unsigned long long below = (1ull << lane) - 1ull;
  int pA = __popcll(mh0 & below);
  int pB = __popcll(mh1 & below);
  int pC = __popcll(mh2 & below);
  int pD = __popcll(mh3 & below);
  int hbA = pA;
  int hbB = nh0 + pB;
  int hbC = nh0 + nh1 + pC;
  int hbD = nh0 + nh1 + nh2 + pD;
  int ebA = lane - pA;
  int ebB = (64 - nh0) + (lane - pB);
  int ebC = (128 - nh0 - nh1) + (lane - pC);
  int ebD = (192 - nh0 - nh1 - nh2) + (lane - pD);
  if (hardA) hardList[baseH + hbA] = (unsigned)gA;
  else       easyList[baseE + ebA] = (unsigned)gA;
  if (hardB) hardList[baseH + hbB] = (unsigned)gB;
  else       easyList[baseE + ebB] = (unsigned)gB;
  if (hardC) hardList[baseH + hbC] = (unsigned)gC;
  else       easyList[baseE + ebC] = (unsigned)gC;
  if (hardD) hardList[baseH + hbD] = (unsigned)gD;
  else       easyList[baseE + ebD] = (unsigned)gD;
}

// ---------------------------------------------------------------------------
// Gather helper (raw pointer, stride 104)
// ---------------------------------------------------------------------------
__device__ __forceinline__ void build_inp_row(
    const float* __restrict__ featT, const float* __restrict__ coord,
    const float* __restrict__ cell, unsigned g, int p, int q8,
    unsigned short* __restrict__ sInpB)  // [*][104]
{
  int b = g / (HO * WO);
  float gy = coord[(size_t)g * 2 + 0];
  float gx = coord[(size_t)g * 2 + 1];
  int iy, ix; nearest_idx(gy, gx, iy, ix);
  const float* fpt = featT + (((size_t)b * PLANE) + iy * WL + ix) * 64 + q8 * 8;
  float4 u0 = *(const float4*)fpt;
  float4 u1 = *(const float4*)(fpt + 4);
  us8 pk;
  pk[0]=f2b(u0.x); pk[1]=f2b(u0.y); pk[2]=f2b(u0.z); pk[3]=f2b(u0.w);
  pk[4]=f2b(u1.x); pk[5]=f2b(u1.y); pk[6]=f2b(u1.z); pk[7]=f2b(u1.w);
  *(us8*)&sInpB[p * 104 + q8 * 8] = pk;
  if (q8 == 0) {
    float cy = (2.f * iy + 1.f) / HL - 1.f;
    float cx = (2.f * ix + 1.f) / WL - 1.f;
    float e0 = (gy - cy) * HL, e1 = (gx - cx) * WL;
    float e2 = cell[(size_t)g * 2 + 0] * HL, e3 = cell[(size_t)g * 2 + 1] * WL;
    us4 pe; pe[0]=f2b(e0); pe[1]=f2b(e1); pe[2]=f2b(e2); pe[3]=f2b(e3);
    *(us4*)&sInpB[p * 104 + 64] = pe;
  }
  if (q8 == 1) {
    us4 z = (us4){0,0,0,0};
    #pragma unroll
    for (int c = 0; c < 9; ++c) *(us4*)&sInpB[p * 104 + 68 + c * 4] = z;
  }
}

// ---------------------------------------------------------------------------
// Merged heavy+light, dynamic LDS (~70KB) — r22 proven.
// ---------------------------------------------------------------------------
#define HLDS (128*264*2 + 128*4*4 + 128*4)   // 70144 B

__global__ __launch_bounds__(512, 2) void ml2_k(
    const float* __restrict__ featT, const float* __restrict__ coord,
    const float* __restrict__ cell,  const float* __restrict__ lrimg,
    const float* __restrict__ lb1, const float* __restrict__ lb2,
    const float* __restrict__ lb3,
    const unsigned short* __restrict__ lw1T, const unsigned short* __restrict__ lw2T,
    const unsigned short* __restrict__ lw3T,
    const float* __restrict__ hb1, const float* __restrict__ hmb,
    const float* __restrict__ hbo,
    const unsigned short* __restrict__ hw1T, const unsigned short* __restrict__ hm0T,
    const unsigned short* __restrict__ hm1T, const unsigned short* __restrict__ hwoT,
    const int* __restrict__ counters,
    const unsigned* __restrict__ easyList, const unsigned* __restrict__ hardList,
    float* __restrict__ out)
{
  extern __shared__ char smem[];
  const int t = threadIdx.x, lane = t & 63, w = t >> 6;

  if (blockIdx.x < HG2) {
    unsigned short* sBuf = (unsigned short*)smem;
    float (*sP)[4]       = (float (*)[4])(smem + 128*264*2);
    unsigned* sIdx       = (unsigned*)(smem + 128*264*2 + 128*16);

    const int nH = counters[1];
    const int g0 = blockIdx.x * 128;
    if (g0 >= nH) return;

    {
      const int p = t >> 2, q = t & 3;
      int i = g0 + p; if (i > nH - 1) i = nH - 1;
      unsigned g = hardList[i];
      if (q == 0) sIdx[p] = g;
      build_inp_row(featT, coord, cell, g, p, q * 2,     sBuf);
      build_inp_row(featT, coord, cell, g, p, q * 2 + 1, sBuf);
    }
    __syncthreads();

    { f32x4 acc[8][2];
      mfma_compute<2, 3, 8>(sBuf, 104, hw1T, 96, w * 32, lane, acc);
      __syncthreads();
      mfma_store<2, true, 8>(acc, hb1, sBuf, 264, 0, w * 32, lane); }
    __syncthreads();
    { f32x4 acc[8][2];
      mfma_compute<2, 8, 8>(sBuf, 264, hm0T, 256, w * 32, lane, acc);
      __syncthreads();
      mfma_store<2, true, 8>(acc, hmb, sBuf, 264, 0, w * 32, lane); }
    __syncthreads();
    { f32x4 acc[8][2];
      mfma_compute<2, 8, 8>(sBuf, 264, hm1T, 256, w * 32, lane, acc);
      __syncthreads();
      mfma_store<2, true, 8>(acc, hmb + 256, sBuf, 264, 0, w * 32, lane); }
    __syncthreads();
    mfma_out3w<8>(sBuf, 264, hwoT, 256, hbo, sP, w, lane);
    __syncthreads();

    if (t < 384) {
      int p = t / 3, ch = t % 3;
      int i = g0 + p;
      if (i < nH) {
        unsigned g = sIdx[p];
        int b = g / (HO * WO);
        int rem = g % (HO * WO);
        int oy = rem / WO, ox = rem % WO;
        float gy = coord[(size_t)g * 2 + 0];
        float gx = coord[(size_t)g * 2 + 1];
        float v = bilinear_lr(lrimg, b, ch, gy, gx);
        out[(((size_t)b * 3 + ch) * HO + oy) * WO + ox] = sP[p][ch] + v;
      }
    }
  } else {
    unsigned short* sInpB = (unsigned short*)smem;              // 64*104
    unsigned short* sL1   = (unsigned short*)(smem + 13312);    // 64*72
    unsigned short* sL2   = (unsigned short*)(smem + 13312 + 9216);
    float (*sP)[4]        = (float (*)[4])(smem + 13312 + 2*9216);
    unsigned* sIdx        = (unsigned*)(smem + 13312 + 2*9216 + 1024);

    const int nE = counters[0];
    const int g0 = (blockIdx.x - HG2) * 64;
    if (g0 >= nE) return;

    if (t < 256) {
      const int p = t >> 2, q = t & 3;
      int i = g0 + p; if (i > nE - 1) i = nE - 1;
      unsigned g = easyList[i];
      if (q == 0) sIdx[p] = g;
      build_inp_row(featT, coord, cell, g, p, q * 2,     sInpB);
      build_inp_row(featT, coord, cell, g, p, q * 2 + 1, sInpB);
    }
    __syncthreads();

    if (w < 4) {
      f32x4 acc[4][1];
      mfma_compute<1, 3, 4>(sInpB, 104, lw1T, 96, w * 16, lane, acc);
      mfma_store<1, true, 4>(acc, lb1, sL1, 72, 0, w * 16, lane);
    }
    __syncthreads();
    if (w < 4) {
      f32x4 acc[4][1];
      mfma_compute<1, 2, 4>(sL1, 72, lw2T, 64, w * 16, lane, acc);
      mfma_store<1, true, 4>(acc, lb2, sL2, 72, 0, w * 16, lane);
    }
    __syncthreads();
    if (w < 4) mfma_out3w<2>(sL2, 72, lw3T, 64, lb3, sP, w, lane);
    __syncthreads();

    if (t < 192) {
      int p = t / 3, ch = t % 3;
      int i = g0 + p;
      if (i < nE) {
        unsigned g = sIdx[p];
        int b = g / (HO * WO);
        int rem = g % (HO * WO);
        int oy = rem / WO, ox = rem % WO;
        float gy = coord[(size_t)g * 2 + 0];
        float gx = coord[(size_t)g * 2 + 1];
        float v = bilinear_lr(lrimg, b, ch, gy, gx);
        out[(((size_t)b * 3 + ch) * HO + oy) * WO + ox] = sP[p][ch] + v;
      }
    }
  }
}

__global__ void finalize_k(const int* __restrict__ counters, float* __restrict__ out)
{
  out[(size_t)NPIX * 3] = (float)(counters[0]) / (float)NPIX;
}

// ---------------------------------------------------------------------------
extern "C" void kernel_launch(void* const* d_in, const int* in_sizes, int n_in,
                              void* d_out, int out_size, void* d_ws, size_t ws_size,
                              hipStream_t stream)
{
  const float* lr       = (const float*)d_in[0];
  const float* coord    = (const float*)d_in[1];
  const float* cell     = (const float*)d_in[2];
  const float* enc_w_in = (const float*)d_in[3];
  const float* enc_b_in = (const float*)d_in[4];
  const float* enc_rw   = (const float*)d_in[5];
  const float* enc_rb   = (const float*)d_in[6];
  const float* cw1      = (const float*)d_in[7];
  const float* cb1      = (const float*)d_in[8];
  const float* cw2      = (const float*)d_in[9];
  const float* cb2      = (const float*)d_in[10];
  const float* lw1      = (const float*)d_in[11];
  const float* lb1      = (const float*)d_in[12];
  const float* lw2      = (const float*)d_in[13];
  const float* lb2      = (const float*)d_in[14];
  const float* lw3      = (const float*)d_in[15];
  const float* lb3      = (const float*)d_in[16];
  const float* hw1      = (const float*)d_in[17];
  const float* hb1      = (const float*)d_in[18];
  const float* hmw      = (const float*)d_in[19];
  const float* hmb      = (const float*)d_in[20];
  const float* hwo      = (const float*)d_in[21];
  const float* hbo      = (const float*)d_in[22];
  float* out = (float*)d_out;

  char* ws = (char*)d_ws;
  float* xA    = (float*)(ws + 1024);
  float* tmp   = xA  + FEAT_ELEMS;
  float* xB    = tmp + FEAT_ELEMS;
  float* featT = tmp;                 // aliases tmp (free after last res conv)
  unsigned short* wb = (unsigned short*)(xB + FEAT_ELEMS);
  unsigned short* lw1T = wb;              // 64*96
  unsigned short* lw2T = lw1T + 64*96;    // 64*64
  unsigned short* lw3T = lw2T + 64*64;    // 16*64
  unsigned short* hw1T = lw3T + 16*64;    // 256*96
  unsigned short* hm0T = hw1T + 256*96;   // 256*256
  unsigned short* hm1T = hm0T + 65536;    // 256*256
  unsigned short* hwoT = hm1T + 65536;    // 16*256
  const size_t nb16 = 64*96 + 64*64 + 16*64 + 256*96 + 2*65536 + 16*256; // 171008
  float* cwIn  = (float*)(wb + nb16);     // 27*64 = 1728
  float* cwRes = cwIn + 1728;             // 8 * 36864 (co-grouped layout)
  size_t need = 1024 + 3 * FEAT_ELEMS * sizeof(float)
              + nb16 * 2 + (1728 + 8 * 36864) * sizeof(float);
  if (ws_size < need) return;

  int*      counters = (int*)xB;
  unsigned* easyList = (unsigned*)(xB + 16);
  unsigned* hardList = easyList + NPIX;

  // allow >64KB dynamic LDS for the merged kernel
  hipFuncSetAttribute((const void*)ml2_k,
                      hipFuncAttributeMaxDynamicSharedMemorySize, HLDS);

  prep_all_k<<<(PREP_TOTAL + 255) / 256, 256, 0, stream>>>(
      lw1, lw2, lw3, hw1, hmw, hwo, enc_w_in, enc_rw,
      lw1T, lw2T, lw3T, hw1T, hm0T, hm1T, hwoT, cwIn, cwRes);

  // --- encoder (fp32; LDS-weight residual convs; ends with feat in xA) ---
  dim3 cgrid(36, 16, 2);
  conv_s_k<3, 4, false, false><<<cgrid, 256, 0, stream>>>(lr, cwIn, enc_b_in, nullptr, xA);

  float* cur = xA; float* oth = xB;
  for (int i = 0; i < 4; ++i) {
    const float* wp0 = cwRes + (size_t)(2 * i)     * 36864;
    const float* wp1 = cwRes + (size_t)(2 * i + 1) * 36864;
    const float* b0 = enc_rb + i * 128;
    const float* b1 = b0 + 64;
    conv_lw_k<true,  false><<<cgrid, 256, 0, stream>>>(cur, wp0, b0, nullptr, tmp);
    conv_lw_k<false, true ><<<cgrid, 256, 0, stream>>>(tmp, wp1, b1, cur, oth);
    float* sw2p = cur; cur = oth; oth = sw2p;
  }
  // cur == xA -> xB free for lists

  nchw_to_nhwc_k<<<dim3(144, 2), 256, 0, stream>>>(cur, featT);

  hipMemsetAsync(counters, 0, 16, stream);

  cls_gate4_k<<<NPIX / 1024, 256, 0, stream>>>(featT, coord, cell,
      cw1, cb1, cw2, cb2, counters, easyList, hardList);

  ml2_k<<<HG2 + LG2, 512, HLDS, stream>>>(featT, coord, cell, lr,
      lb1, lb2, lb3, lw1T, lw2T, lw3T,
      hb1, hmb, hbo, hw1T, hm0T, hm1T, hwoT,
      counters, easyList, hardList, out);

  finalize_k<<<1, 1, 0, stream>>>(counters, out);
}

// Round 24
// 568.877 us; speedup vs baseline: 1.1717x; 1.1717x over previous
//
#include <hip/hip_runtime.h>

#define HL 96
#define WL 96
#define HO 384
#define WO 384
#define NPIX (2*HO*WO)           // 294912 output pixels (B=2)
#define FEAT_ELEMS ((size_t)2*64*HL*WL)  // 1179648
#define PLANE (HL*WL)            // 9216
#define HG2 (NPIX/128)           // 2304 heavy blocks
#define LG2 (NPIX/64)            // 4608 light blocks

typedef unsigned short us4 __attribute__((ext_vector_type(4)));
typedef unsigned short us8 __attribute__((ext_vector_type(8)));
typedef __bf16         b8  __attribute__((ext_vector_type(8)));
typedef float          f32x4 __attribute__((ext_vector_type(4)));

__device__ __forceinline__ unsigned short f2b(float x) {
  unsigned u = __builtin_bit_cast(unsigned, x);
  unsigned r = (u + 0x7FFFu + ((u >> 16) & 1u)) >> 16;
  return (unsigned short)r;
}

__device__ __forceinline__ f32x4 MF(us8 a, us8 b, f32x4 c) {
  return __builtin_amdgcn_mfma_f32_16x16x32_bf16(
      __builtin_bit_cast(b8, a), __builtin_bit_cast(b8, b), c, 0, 0, 0);
}

// ---------------------------------------------------------------------------
// First conv (CIN=3): scalar-weight version — proven.
// ---------------------------------------------------------------------------
template<int CIN, int COPT, bool RELU, bool RES>
__global__ __launch_bounds__(256) void conv_s_k(
    const float* __restrict__ in, const float* __restrict__ wP,
    const float* __restrict__ bias, const float* __restrict__ res,
    float* __restrict__ out)
{
  const int t   = threadIdx.x;
  const int p   = blockIdx.x * 256 + t;
  const int co0 = blockIdx.y * COPT;
  const int b   = blockIdx.z;
  const int x   = p % WL;
  const bool xl = (x == 0), xr = (x == WL - 1);

  float acc[COPT];
  #pragma unroll
  for (int j = 0; j < COPT; ++j) acc[j] = bias[co0 + j];

  int  ic[3]; bool yv[3];
  int  im[3], ip[3];
  #pragma unroll
  for (int ky = 0; ky < 3; ++ky) {
    int pr = p + (ky - 1) * WL;
    yv[ky] = ((unsigned)pr < (unsigned)PLANE);
    ic[ky] = yv[ky] ? pr : 0;
    im[ky] = ic[ky] - 1; if (im[ky] < 0) im[ky] = 0;
    ip[ky] = ic[ky] + 1; if (ip[ky] > PLANE - 1) ip[ky] = PLANE - 1;
  }

  const float* inb = in + (size_t)b * CIN * PLANE;

  #pragma unroll 2
  for (int ci = 0; ci < CIN; ++ci) {
    const float* pl = inb + (size_t)ci * PLANE;
    #pragma unroll
    for (int ky = 0; ky < 3; ++ky) {
      float am = pl[im[ky]];
      float a0 = pl[ic[ky]];
      float ap = pl[ip[ky]];
      if (!yv[ky]) { am = 0.f; a0 = 0.f; ap = 0.f; }
      if (xl) am = 0.f;
      if (xr) ap = 0.f;
      const float* wrow = wP + (size_t)(ci * 9 + ky * 3) * 64 + co0;
      #pragma unroll
      for (int j = 0; j < COPT; ++j) acc[j] += am * wrow[j];
      #pragma unroll
      for (int j = 0; j < COPT; ++j) acc[j] += a0 * wrow[64 + j];
      #pragma unroll
      for (int j = 0; j < COPT; ++j) acc[j] += ap * wrow[128 + j];
    }
  }

  size_t ob = ((size_t)b * 64 + co0) * PLANE + p;
  #pragma unroll
  for (int j = 0; j < COPT; ++j) {
    float v = acc[j];
    if (RELU) v = fmaxf(v, 0.f);
    if (RES)  v += res[ob + (size_t)j * PLANE];
    out[ob + (size_t)j * PLANE] = v;
  }
}

// ---------------------------------------------------------------------------
// Residual conv (CIN=64): LDS-staged weights (r15-measured best).
// ---------------------------------------------------------------------------
template<bool RELU, bool RES>
__global__ __launch_bounds__(256) void conv_lw_k(
    const float* __restrict__ in, const float* __restrict__ wG,
    const float* __restrict__ bias, const float* __restrict__ res,
    float* __restrict__ out)
{
  __shared__ float sw[576 * 4];

  const int t   = threadIdx.x;
  const int p   = blockIdx.x * 256 + t;
  const int co0 = blockIdx.y * 4;
  const int b   = blockIdx.z;
  const int x   = p % WL;
  const bool xl = (x == 0), xr = (x == WL - 1);

  {
    const float4* s4 = (const float4*)(wG + (size_t)blockIdx.y * 2304);
    float4* d4 = (float4*)sw;
    for (int i = t; i < 576; i += 256) d4[i] = s4[i];
  }

  float acc[4];
  #pragma unroll
  for (int j = 0; j < 4; ++j) acc[j] = bias[co0 + j];

  int  ic[3]; bool yv[3];
  int  im[3], ip[3];
  #pragma unroll
  for (int ky = 0; ky < 3; ++ky) {
    int pr = p + (ky - 1) * WL;
    yv[ky] = ((unsigned)pr < (unsigned)PLANE);
    ic[ky] = yv[ky] ? pr : 0;
    im[ky] = ic[ky] - 1; if (im[ky] < 0) im[ky] = 0;
    ip[ky] = ic[ky] + 1; if (ip[ky] > PLANE - 1) ip[ky] = PLANE - 1;
  }

  const float* inb = in + (size_t)b * 64 * PLANE;
  __syncthreads();

  #pragma unroll 2
  for (int ci = 0; ci < 64; ++ci) {
    const float* pl = inb + (size_t)ci * PLANE;
    #pragma unroll
    for (int ky = 0; ky < 3; ++ky) {
      float am = pl[im[ky]];
      float a0 = pl[ic[ky]];
      float ap = pl[ip[ky]];
      if (!yv[ky]) { am = 0.f; a0 = 0.f; ap = 0.f; }
      if (xl) am = 0.f;
      if (xr) ap = 0.f;
      const float* wrow = &sw[(ci * 9 + ky * 3) * 4];
      #pragma unroll
      for (int j = 0; j < 4; ++j) acc[j] += am * wrow[j];
      #pragma unroll
      for (int j = 0; j < 4; ++j) acc[j] += a0 * wrow[4 + j];
      #pragma unroll
      for (int j = 0; j < 4; ++j) acc[j] += ap * wrow[8 + j];
    }
  }

  size_t ob = ((size_t)b * 64 + co0) * PLANE + p;
  #pragma unroll
  for (int j = 0; j < 4; ++j) {
    float v = acc[j];
    if (RELU) v = fmaxf(v, 0.f);
    if (RES)  v += res[ob + (size_t)j * PLANE];
    out[ob + (size_t)j * PLANE] = v;
  }
}

// ---------------------------------------------------------------------------
// ONE fused prep kernel
// ---------------------------------------------------------------------------
__device__ __forceinline__ void prep_bf16(const float* __restrict__ src,
    unsigned short* __restrict__ dst, int K, int N, int Kp, int i)
{
  int n = i / Kp, k = i - n * Kp;
  float v = (k < K && n < N) ? src[(size_t)k * N + n] : 0.f;
  dst[i] = f2b(v);
}
__device__ __forceinline__ void prep_conv(const float* __restrict__ src,
    float* __restrict__ dst, int cin, int i)
{
  int co = i % 64; int r = i / 64;
  int ci = r / 9, tap = r % 9;
  dst[i] = src[((size_t)co * cin + ci) * 9 + tap];
}
// co-grouped layout for conv_lw_k
__device__ __forceinline__ void prep_conv2(const float* __restrict__ src,
    float* __restrict__ dst, int i)
{
  int j  = i & 3;
  int t2 = i >> 2;
  int cg = t2 / 576;
  int r  = t2 - cg * 576;
  int ci = r / 9, tap = r - ci * 9;
  int co = cg * 4 + j;
  dst[i] = src[((size_t)co * 64 + ci) * 9 + tap];
}

#define PREP_TOTAL 467648
__global__ __launch_bounds__(256) void prep_all_k(
    const float* __restrict__ lw1, const float* __restrict__ lw2,
    const float* __restrict__ lw3, const float* __restrict__ hw1,
    const float* __restrict__ hmw, const float* __restrict__ hwo,
    const float* __restrict__ enc_w_in, const float* __restrict__ enc_rw,
    unsigned short* __restrict__ lw1T, unsigned short* __restrict__ lw2T,
    unsigned short* __restrict__ lw3T, unsigned short* __restrict__ hw1T,
    unsigned short* __restrict__ hm0T, unsigned short* __restrict__ hm1T,
    unsigned short* __restrict__ hwoT, float* __restrict__ cwIn,
    float* __restrict__ cwRes)
{
  int i = blockIdx.x * 256 + threadIdx.x;
  if (i >= PREP_TOTAL) return;
  if (i < 6144)  { prep_bf16(lw1, lw1T, 68, 64, 96, i);    return; } i -= 6144;
  if (i < 4096)  { prep_bf16(lw2, lw2T, 64, 64, 64, i);    return; } i -= 4096;
  if (i < 1024)  { prep_bf16(lw3, lw3T, 64, 3, 64, i);     return; } i -= 1024;
  if (i < 24576) { prep_bf16(hw1, hw1T, 68, 256, 96, i);   return; } i -= 24576;
  if (i < 65536) { prep_bf16(hmw, hm0T, 256, 256, 256, i); return; } i -= 65536;
  if (i < 65536) { prep_bf16(hmw + 65536, hm1T, 256, 256, 256, i); return; } i -= 65536;
  if (i < 4096)  { prep_bf16(hwo, hwoT, 256, 3, 256, i);   return; } i -= 4096;
  if (i < 1728)  { prep_conv(enc_w_in, cwIn, 3, i);        return; } i -= 1728;
  int l = i / 36864, r = i % 36864;
  prep_conv2(enc_rw + (size_t)l * 36864, cwRes + (size_t)l * 36864, r);
}

__global__ __launch_bounds__(256) void nchw_to_nhwc_k(const float* __restrict__ in,
                                                      float* __restrict__ out)
{
  __shared__ float s[64][65];
  const int b = blockIdx.y;
  const int pix0 = blockIdx.x * 64;
  const int t = threadIdx.x;
  #pragma unroll
  for (int cc = 0; cc < 16; ++cc) {
    int co = cc * 4 + (t >> 6);
    int px = t & 63;
    s[px][co] = in[((size_t)b * 64 + co) * PLANE + pix0 + px];
  }
  __syncthreads();
  #pragma unroll
  for (int pp = 0; pp < 16; ++pp) {
    int px = pp * 4 + (t >> 6);
    int co = t & 63;
    out[((size_t)b * PLANE + pix0 + px) * 64 + co] = s[px][co];
  }
}

// ---------------------------------------------------------------------------
// MFMA helpers, parametrized on MT (m-tiles per wave)
// ---------------------------------------------------------------------------
template<int NT, int KT, int MT>
__device__ __forceinline__ void mfma_compute(
    const unsigned short* __restrict__ aBase, int AS,
    const unsigned short* __restrict__ WT, int Kpad,
    int n0, int lane, f32x4 (&acc)[MT][NT])
{
  const int lr = lane & 15;
  const int lc = lane >> 4;
  #pragma unroll
  for (int m = 0; m < MT; ++m)
    #pragma unroll
    for (int j = 0; j < NT; ++j) acc[m][j] = (f32x4){0.f, 0.f, 0.f, 0.f};

  const unsigned short* aP = aBase + lr * AS + lc * 8;
  const unsigned short* bP = WT + (size_t)(n0 + lr) * Kpad + lc * 8;

  constexpr int KCH = (KT >= 4) ? 4 : KT;
  #pragma unroll
  for (int kc = 0; kc < KT; kc += KCH) {
    us8 breg[KCH][NT];
    #pragma unroll
    for (int kk = 0; kk < KCH; ++kk)
      #pragma unroll
      for (int j = 0; j < NT; ++j)
        breg[kk][j] = *(const us8*)(bP + (size_t)j * 16 * Kpad + (kc + kk) * 32);
    #pragma unroll
    for (int kc2 = 0; kc2 < KCH; ++kc2) {
      us8 a0[MT];
      #pragma unroll
      for (int m = 0; m < MT; ++m)
        a0[m] = *(const us8*)(aP + (m * 16) * AS + (kc + kc2) * 32);
      #pragma unroll
      for (int m = 0; m < MT; ++m)
        #pragma unroll
        for (int j = 0; j < NT; ++j)
          acc[m][j] = MF(a0[m], breg[kc2][j], acc[m][j]);
    }
  }
}

template<int NT, bool RELU, int MT>
__device__ __forceinline__ void mfma_store(
    const f32x4 (&acc)[MT][NT], const float* __restrict__ bias,
    unsigned short* __restrict__ dBase, int DS, int dCol0, int n0, int lane)
{
  const int lr = lane & 15;
  const int lc = lane >> 4;
  #pragma unroll
  for (int j = 0; j < NT; ++j) {
    int n = n0 + j * 16 + lr;
    float bv = bias[n];
    #pragma unroll
    for (int m = 0; m < MT; ++m)
      #pragma unroll
      for (int r = 0; r < 4; ++r) {
        float v = acc[m][j][r] + bv;
        if (RELU) v = fmaxf(v, 0.f);
        dBase[(m * 16 + lc * 4 + r) * DS + dCol0 + n] = f2b(v);
      }
  }
}

template<int KT>
__device__ __forceinline__ void mfma_out3w(
    const unsigned short* __restrict__ aBase, int AS,
    const unsigned short* __restrict__ WT, int Kpad,
    const float* __restrict__ bias, float (*dst)[4], int mtile, int lane)
{
  const int lr = lane & 15;
  const int lc = lane >> 4;
  f32x4 acc = (f32x4){0.f, 0.f, 0.f, 0.f};
  const unsigned short* aP = aBase + (mtile * 16 + lr) * AS + lc * 8;
  const unsigned short* bP = WT + (size_t)lr * Kpad + lc * 8;

  constexpr int KCH = (KT >= 4) ? 4 : KT;
  #pragma unroll
  for (int kc = 0; kc < KT; kc += KCH) {
    us8 breg[KCH];
    #pragma unroll
    for (int kk = 0; kk < KCH; ++kk)
      breg[kk] = *(const us8*)(bP + (kc + kk) * 32);
    #pragma unroll
    for (int kk = 0; kk < KCH; ++kk) {
      us8 a = *(const us8*)(aP + (kc + kk) * 32);
      acc = MF(a, breg[kk], acc);
    }
  }
  if (lr < 3) {
    float bv = bias[lr];
    #pragma unroll
    for (int r = 0; r < 4; ++r)
      dst[mtile * 16 + lc * 4 + r][lr] = acc[r] + bv;
  }
}

// ---------------------------------------------------------------------------
// Shared helpers
// ---------------------------------------------------------------------------
__device__ __forceinline__ void nearest_idx(float gy, float gx, int& iy, int& ix)
{
  float fy = (gy + 1.f) * (HL * 0.5f) - 0.5f;
  float fx = (gx + 1.f) * (WL * 0.5f) - 0.5f;
  iy = min(max((int)floorf(fy + 0.5f), 0), HL - 1);
  ix = min(max((int)floorf(fx + 0.5f), 0), WL - 1);
}

__device__ __forceinline__ float bilinear_lr(const float* __restrict__ lrimg,
                                             int b, int ch, float gy, float gx)
{
  float x = (gx + 1.f) * (WL * 0.5f) - 0.5f;
  float y = (gy + 1.f) * (HL * 0.5f) - 0.5f;
  float xf = floorf(x), yf = floorf(y);
  float wx = x - xf, wy = y - yf;
  int x0i = min(max((int)xf,     0), WL - 1);
  int x1i = min(max((int)xf + 1, 0), WL - 1);
  int y0i = min(max((int)yf,     0), HL - 1);
  int y1i = min(max((int)yf + 1, 0), HL - 1);
  const float* img = lrimg + ((size_t)b * 3 + ch) * PLANE;
  float v00 = img[y0i * WL + x0i], v01 = img[y0i * WL + x1i];
  float v10 = img[y1i * WL + x0i], v11 = img[y1i * WL + x1i];
  return v00 * (1.f - wx) * (1.f - wy) + v01 * wx * (1.f - wy)
       + v10 * (1.f - wx) * wy + v11 * wx * wy;
}

// ---------------------------------------------------------------------------
// Pass 1 (v5, r14/r22 proven): scalar-weight classifier, 2 px/thread.
// Global-memory weights; 32 VGPR-resident accumulators; zero spill.
// FROZEN: LDS-weights (r20) and 4px/thread (r23) both spilled to scratch.
// ---------------------------------------------------------------------------
template<int JB>
__device__ __forceinline__ void cls_block2(
    const float* __restrict__ fpA, const float* __restrict__ fpB,
    const float4& eA, const float4& eB,
    const float* __restrict__ cw1, const float* __restrict__ cb1,
    const float* __restrict__ cw2, int j0,
    float& l0a, float& l1a, float& l0b, float& l1b)
{
  float accA[JB], accB[JB];
  #pragma unroll
  for (int j = 0; j < JB; ++j) { accA[j] = cb1[j0 + j]; accB[j] = accA[j]; }
  #pragma unroll 4
  for (int kq = 0; kq < 16; ++kq) {
    float4 a4A = *(const float4*)(fpA + kq * 4);
    float4 a4B = *(const float4*)(fpB + kq * 4);
    float avA[4] = {a4A.x, a4A.y, a4A.z, a4A.w};
    float avB[4] = {a4B.x, a4B.y, a4B.z, a4B.w};
    #pragma unroll
    for (int kk = 0; kk < 4; ++kk) {
      const float* wr = cw1 + (size_t)(kq * 4 + kk) * 64 + j0;
      float aA = avA[kk], aB = avB[kk];
      #pragma unroll
      for (int j = 0; j < JB; ++j) { accA[j] += aA * wr[j]; accB[j] += aB * wr[j]; }
    }
  }
  {
    const float* wr = cw1 + (size_t)64 * 64 + j0;
    #pragma unroll
    for (int j = 0; j < JB; ++j) { accA[j] += eA.x * wr[j]; accB[j] += eB.x * wr[j]; }
    wr += 64;
    #pragma unroll
    for (int j = 0; j < JB; ++j) { accA[j] += eA.y * wr[j]; accB[j] += eB.y * wr[j]; }
    wr += 64;
    #pragma unroll
    for (int j = 0; j < JB; ++j) { accA[j] += eA.z * wr[j]; accB[j] += eB.z * wr[j]; }
    wr += 64;
    #pragma unroll
    for (int j = 0; j < JB; ++j) { accA[j] += eA.w * wr[j]; accB[j] += eB.w * wr[j]; }
  }
  #pragma unroll
  for (int j = 0; j < JB; ++j) {
    float hA = fmaxf(accA[j], 0.f);
    float hB = fmaxf(accB[j], 0.f);
    float w0 = cw2[(j0 + j) * 2 + 0], w1 = cw2[(j0 + j) * 2 + 1];
    l0a += hA * w0; l1a += hA * w1;
    l0b += hB * w0; l1b += hB * w1;
  }
}

__global__ __launch_bounds__(256, 4) void cls_gate2_k(
    const float* __restrict__ featT, const float* __restrict__ coord,
    const float* __restrict__ cell,
    const float* __restrict__ cw1, const float* __restrict__ cb1,
    const float* __restrict__ cw2, const float* __restrict__ cb2,
    int* __restrict__ counters, unsigned* __restrict__ easyList,
    unsigned* __restrict__ hardList)
{
  const int T  = blockIdx.x * 256 + threadIdx.x;
  const int gA = T * 2, gB = gA + 1;

  int bA = gA / (HO * WO);
  float gyA = coord[(size_t)gA * 2 + 0];
  float gxA = coord[(size_t)gA * 2 + 1];
  int iyA, ixA; nearest_idx(gyA, gxA, iyA, ixA);
  const float* fpA = featT + (((size_t)bA * PLANE) + iyA * WL + ixA) * 64;
  float4 eA;
  { float cy = (2.f * iyA + 1.f) / HL - 1.f;
    float cx = (2.f * ixA + 1.f) / WL - 1.f;
    eA.x = (gyA - cy) * HL; eA.y = (gxA - cx) * WL;
    eA.z = cell[(size_t)gA * 2 + 0] * HL; eA.w = cell[(size_t)gA * 2 + 1] * WL; }

  int bB = gB / (HO * WO);
  float gyB = coord[(size_t)gB * 2 + 0];
  float gxB = coord[(size_t)gB * 2 + 1];
  int iyB, ixB; nearest_idx(gyB, gxB, iyB, ixB);
  const float* fpB = featT + (((size_t)bB * PLANE) + iyB * WL + ixB) * 64;
  float4 eB;
  { float cy = (2.f * iyB + 1.f) / HL - 1.f;
    float cx = (2.f * ixB + 1.f) / WL - 1.f;
    eB.x = (gyB - cy) * HL; eB.y = (gxB - cx) * WL;
    eB.z = cell[(size_t)gB * 2 + 0] * HL; eB.w = cell[(size_t)gB * 2 + 1] * WL; }

  float l0a = cb2[0], l1a = cb2[1];
  float l0b = cb2[0], l1b = cb2[1];
  cls_block2<32>(fpA, fpB, eA, eB, cw1, cb1, cw2, 0,  l0a, l1a, l0b, l1b);
  cls_block2<32>(fpA, fpB, eA, eB, cw1, cb1, cw2, 32, l0a, l1a, l0b, l1b);
  bool hardA = (l1a > l0a);
  bool hardB = (l1b > l0b);

  unsigned long long mh0 = __ballot(hardA);
  unsigned long long mh1 = __ballot(hardB);
  int lane = threadIdx.x & 63;
  int nh0 = __popcll(mh0), nh1 = __popcll(mh1);
  int nh = nh0 + nh1;
  int baseH = 0, baseE = 0;
  if (lane == 0) {
    baseH = atomicAdd(&counters[1], nh);
    baseE = atomicAdd(&counters[0], 128 - nh);
  }
  baseH = __shfl(baseH, 0);
  baseE = __shfl(baseE, 0);
  unsigned long long below = (1ull << lane) - 1ull;
  int hbA = __popcll(mh0 & below);
  int hbB = nh0 + __popcll(mh1 & below);
  int ebA = lane - hbA;
  int ebB = (64 - nh0) + (lane - __popcll(mh1 & below));
  if (hardA) hardList[baseH + hbA] = (unsigned)gA;
  else       easyList[baseE + ebA] = (unsigned)gA;
  if (hardB) hardList[baseH + hbB] = (unsigned)gB;
  else       easyList[baseE + ebB] = (unsigned)gB;
}

// ---------------------------------------------------------------------------
// Gather helper (raw pointer, stride 104)
// ---------------------------------------------------------------------------
__device__ __forceinline__ void build_inp_row(
    const float* __restrict__ featT, const float* __restrict__ coord,
    const float* __restrict__ cell, unsigned g, int p, int q8,
    unsigned short* __restrict__ sInpB)  // [*][104]
{
  int b = g / (HO * WO);
  float gy = coord[(size_t)g * 2 + 0];
  float gx = coord[(size_t)g * 2 + 1];
  int iy, ix; nearest_idx(gy, gx, iy, ix);
  const float* fpt = featT + (((size_t)b * PLANE) + iy * WL + ix) * 64 + q8 * 8;
  float4 u0 = *(const float4*)fpt;
  float4 u1 = *(const float4*)(fpt + 4);
  us8 pk;
  pk[0]=f2b(u0.x); pk[1]=f2b(u0.y); pk[2]=f2b(u0.z); pk[3]=f2b(u0.w);
  pk[4]=f2b(u1.x); pk[5]=f2b(u1.y); pk[6]=f2b(u1.z); pk[7]=f2b(u1.w);
  *(us8*)&sInpB[p * 104 + q8 * 8] = pk;
  if (q8 == 0) {
    float cy = (2.f * iy + 1.f) / HL - 1.f;
    float cx = (2.f * ix + 1.f) / WL - 1.f;
    float e0 = (gy - cy) * HL, e1 = (gx - cx) * WL;
    float e2 = cell[(size_t)g * 2 + 0] * HL, e3 = cell[(size_t)g * 2 + 1] * WL;
    us4 pe; pe[0]=f2b(e0); pe[1]=f2b(e1); pe[2]=f2b(e2); pe[3]=f2b(e3);
    *(us4*)&sInpB[p * 104 + 64] = pe;
  }
  if (q8 == 1) {
    us4 z = (us4){0,0,0,0};
    #pragma unroll
    for (int c = 0; c < 9; ++c) *(us4*)&sInpB[p * 104 + 68 + c * 4] = z;
  }
}

// ---------------------------------------------------------------------------
// Merged heavy+light, dynamic LDS (~70KB) — r22 proven.
// ---------------------------------------------------------------------------
#define HLDS (128*264*2 + 128*4*4 + 128*4)   // 70144 B

__global__ __launch_bounds__(512, 2) void ml2_k(
    const float* __restrict__ featT, const float* __restrict__ coord,
    const float* __restrict__ cell,  const float* __restrict__ lrimg,
    const float* __restrict__ lb1, const float* __restrict__ lb2,
    const float* __restrict__ lb3,
    const unsigned short* __restrict__ lw1T, const unsigned short* __restrict__ lw2T,
    const unsigned short* __restrict__ lw3T,
    const float* __restrict__ hb1, const float* __restrict__ hmb,
    const float* __restrict__ hbo,
    const unsigned short* __restrict__ hw1T, const unsigned short* __restrict__ hm0T,
    const unsigned short* __restrict__ hm1T, const unsigned short* __restrict__ hwoT,
    const int* __restrict__ counters,
    const unsigned* __restrict__ easyList, const unsigned* __restrict__ hardList,
    float* __restrict__ out)
{
  extern __shared__ char smem[];
  const int t = threadIdx.x, lane = t & 63, w = t >> 6;

  if (blockIdx.x < HG2) {
    unsigned short* sBuf = (unsigned short*)smem;
    float (*sP)[4]       = (float (*)[4])(smem + 128*264*2);
    unsigned* sIdx       = (unsigned*)(smem + 128*264*2 + 128*16);

    const int nH = counters[1];
    const int g0 = blockIdx.x * 128;
    if (g0 >= nH) return;

    {
      const int p = t >> 2, q = t & 3;
      int i = g0 + p; if (i > nH - 1) i = nH - 1;
      unsigned g = hardList[i];
      if (q == 0) sIdx[p] = g;
      build_inp_row(featT, coord, cell, g, p, q * 2,     sBuf);
      build_inp_row(featT, coord, cell, g, p, q * 2 + 1, sBuf);
    }
    __syncthreads();

    { f32x4 acc[8][2];
      mfma_compute<2, 3, 8>(sBuf, 104, hw1T, 96, w * 32, lane, acc);
      __syncthreads();
      mfma_store<2, true, 8>(acc, hb1, sBuf, 264, 0, w * 32, lane); }
    __syncthreads();
    { f32x4 acc[8][2];
      mfma_compute<2, 8, 8>(sBuf, 264, hm0T, 256, w * 32, lane, acc);
      __syncthreads();
      mfma_store<2, true, 8>(acc, hmb, sBuf, 264, 0, w * 32, lane); }
    __syncthreads();
    { f32x4 acc[8][2];
      mfma_compute<2, 8, 8>(sBuf, 264, hm1T, 256, w * 32, lane, acc);
      __syncthreads();
      mfma_store<2, true, 8>(acc, hmb + 256, sBuf, 264, 0, w * 32, lane); }
    __syncthreads();
    mfma_out3w<8>(sBuf, 264, hwoT, 256, hbo, sP, w, lane);
    __syncthreads();

    if (t < 384) {
      int p = t / 3, ch = t % 3;
      int i = g0 + p;
      if (i < nH) {
        unsigned g = sIdx[p];
        int b = g / (HO * WO);
        int rem = g % (HO * WO);
        int oy = rem / WO, ox = rem % WO;
        float gy = coord[(size_t)g * 2 + 0];
        float gx = coord[(size_t)g * 2 + 1];
        float v = bilinear_lr(lrimg, b, ch, gy, gx);
        out[(((size_t)b * 3 + ch) * HO + oy) * WO + ox] = sP[p][ch] + v;
      }
    }
  } else {
    unsigned short* sInpB = (unsigned short*)smem;              // 64*104
    unsigned short* sL1   = (unsigned short*)(smem + 13312);    // 64*72
    unsigned short* sL2   = (unsigned short*)(smem + 13312 + 9216);
    float (*sP)[4]        = (float (*)[4])(smem + 13312 + 2*9216);
    unsigned* sIdx        = (unsigned*)(smem + 13312 + 2*9216 + 1024);

    const int nE = counters[0];
    const int g0 = (blockIdx.x - HG2) * 64;
    if (g0 >= nE) return;

    if (t < 256) {
      const int p = t >> 2, q = t & 3;
      int i = g0 + p; if (i > nE - 1) i = nE - 1;
      unsigned g = easyList[i];
      if (q == 0) sIdx[p] = g;
      build_inp_row(featT, coord, cell, g, p, q * 2,     sInpB);
      build_inp_row(featT, coord, cell, g, p, q * 2 + 1, sInpB);
    }
    __syncthreads();

    if (w < 4) {
      f32x4 acc[4][1];
      mfma_compute<1, 3, 4>(sInpB, 104, lw1T, 96, w * 16, lane, acc);
      mfma_store<1, true, 4>(acc, lb1, sL1, 72, 0, w * 16, lane);
    }
    __syncthreads();
    if (w < 4) {
      f32x4 acc[4][1];
      mfma_compute<1, 2, 4>(sL1, 72, lw2T, 64, w * 16, lane, acc);
      mfma_store<1, true, 4>(acc, lb2, sL2, 72, 0, w * 16, lane);
    }
    __syncthreads();
    if (w < 4) mfma_out3w<2>(sL2, 72, lw3T, 64, lb3, sP, w, lane);
    __syncthreads();

    if (t < 192) {
      int p = t / 3, ch = t % 3;
      int i = g0 + p;
      if (i < nE) {
        unsigned g = sIdx[p];
        int b = g / (HO * WO);
        int rem = g % (HO * WO);
        int oy = rem / WO, ox = rem % WO;
        float gy = coord[(size_t)g * 2 + 0];
        float gx = coord[(size_t)g * 2 + 1];
        float v = bilinear_lr(lrimg, b, ch, gy, gx);
        out[(((size_t)b * 3 + ch) * HO + oy) * WO + ox] = sP[p][ch] + v;
      }
    }
  }
}

__global__ void finalize_k(const int* __restrict__ counters, float* __restrict__ out)
{
  out[(size_t)NPIX * 3] = (float)(counters[0]) / (float)NPIX;
}

// ---------------------------------------------------------------------------
extern "C" void kernel_launch(void* const* d_in, const int* in_sizes, int n_in,
                              void* d_out, int out_size, void* d_ws, size_t ws_size,
                              hipStream_t stream)
{
  const float* lr       = (const float*)d_in[0];
  const float* coord    = (const float*)d_in[1];
  const float* cell     = (const float*)d_in[2];
  const float* enc_w_in = (const float*)d_in[3];
  const float* enc_b_in = (const float*)d_in[4];
  const float* enc_rw   = (const float*)d_in[5];
  const float* enc_rb   = (const float*)d_in[6];
  const float* cw1      = (const float*)d_in[7];
  const float* cb1      = (const float*)d_in[8];
  const float* cw2      = (const float*)d_in[9];
  const float* cb2      = (const float*)d_in[10];
  const float* lw1      = (const float*)d_in[11];
  const float* lb1      = (const float*)d_in[12];
  const float* lw2      = (const float*)d_in[13];
  const float* lb2      = (const float*)d_in[14];
  const float* lw3      = (const float*)d_in[15];
  const float* lb3      = (const float*)d_in[16];
  const float* hw1      = (const float*)d_in[17];
  const float* hb1      = (const float*)d_in[18];
  const float* hmw      = (const float*)d_in[19];
  const float* hmb      = (const float*)d_in[20];
  const float* hwo      = (const float*)d_in[21];
  const float* hbo      = (const float*)d_in[22];
  float* out = (float*)d_out;

  char* ws = (char*)d_ws;
  float* xA    = (float*)(ws + 1024);
  float* tmp   = xA  + FEAT_ELEMS;
  float* xB    = tmp + FEAT_ELEMS;
  float* featT = tmp;                 // aliases tmp (free after last res conv)
  unsigned short* wb = (unsigned short*)(xB + FEAT_ELEMS);
  unsigned short* lw1T = wb;              // 64*96
  unsigned short* lw2T = lw1T + 64*96;    // 64*64
  unsigned short* lw3T = lw2T + 64*64;    // 16*64
  unsigned short* hw1T = lw3T + 16*64;    // 256*96
  unsigned short* hm0T = hw1T + 256*96;   // 256*256
  unsigned short* hm1T = hm0T + 65536;    // 256*256
  unsigned short* hwoT = hm1T + 65536;    // 16*256
  const size_t nb16 = 64*96 + 64*64 + 16*64 + 256*96 + 2*65536 + 16*256; // 171008
  float* cwIn  = (float*)(wb + nb16);     // 27*64 = 1728
  float* cwRes = cwIn + 1728;             // 8 * 36864 (co-grouped layout)
  size_t need = 1024 + 3 * FEAT_ELEMS * sizeof(float)
              + nb16 * 2 + (1728 + 8 * 36864) * sizeof(float);
  if (ws_size < need) return;

  int*      counters = (int*)xB;
  unsigned* easyList = (unsigned*)(xB + 16);
  unsigned* hardList = easyList + NPIX;

  // allow >64KB dynamic LDS for the merged kernel
  hipFuncSetAttribute((const void*)ml2_k,
                      hipFuncAttributeMaxDynamicSharedMemorySize, HLDS);

  prep_all_k<<<(PREP_TOTAL + 255) / 256, 256, 0, stream>>>(
      lw1, lw2, lw3, hw1, hmw, hwo, enc_w_in, enc_rw,
      lw1T, lw2T, lw3T, hw1T, hm0T, hm1T, hwoT, cwIn, cwRes);

  // --- encoder (fp32; LDS-weight residual convs; ends with feat in xA) ---
  dim3 cgrid(36, 16, 2);
  conv_s_k<3, 4, false, false><<<cgrid, 256, 0, stream>>>(lr, cwIn, enc_b_in, nullptr, xA);

  float* cur = xA; float* oth = xB;
  for (int i = 0; i < 4; ++i) {
    const float* wp0 = cwRes + (size_t)(2 * i)     * 36864;
    const float* wp1 = cwRes + (size_t)(2 * i + 1) * 36864;
    const float* b0 = enc_rb + i * 128;
    const float* b1 = b0 + 64;
    conv_lw_k<true,  false><<<cgrid, 256, 0, stream>>>(cur, wp0, b0, nullptr, tmp);
    conv_lw_k<false, true ><<<cgrid, 256, 0, stream>>>(tmp, wp1, b1, cur, oth);
    float* sw2p = cur; cur = oth; oth = sw2p;
  }
  // cur == xA -> xB free for lists

  nchw_to_nhwc_k<<<dim3(144, 2), 256, 0, stream>>>(cur, featT);

  hipMemsetAsync(counters, 0, 16, stream);

  cls_gate2_k<<<NPIX / 512, 256, 0, stream>>>(featT, coord, cell,
      cw1, cb1, cw2, cb2, counters, easyList, hardList);

  ml2_k<<<HG2 + LG2, 512, HLDS, stream>>>(featT, coord, cell, lr,
      lb1, lb2, lb3, lw1T, lw2T, lw3T,
      hb1, hmb, hbo, hw1T, hm0T, hm1T, hwoT,
      counters, easyList, hardList, out);

  finalize_k<<<1, 1, 0, stream>>>(counters, out);
}

// Round 25
// 561.180 us; speedup vs baseline: 1.1877x; 1.0137x over previous
//
#include <hip/hip_runtime.h>

#define HL 96
#define WL 96
#define HO 384
#define WO 384
#define NPIX (2*HO*WO)           // 294912 output pixels (B=2)
#define FEAT_ELEMS ((size_t)2*64*HL*WL)  // 1179648
#define PLANE (HL*WL)            // 9216
#define HG2 (NPIX/128)           // 2304 heavy blocks
#define LG2 (NPIX/64)            // 4608 light blocks

typedef unsigned short us4 __attribute__((ext_vector_type(4)));
typedef unsigned short us8 __attribute__((ext_vector_type(8)));
typedef __bf16         b8  __attribute__((ext_vector_type(8)));
typedef float          f32x4 __attribute__((ext_vector_type(4)));

__device__ __forceinline__ unsigned short f2b(float x) {
  unsigned u = __builtin_bit_cast(unsigned, x);
  unsigned r = (u + 0x7FFFu + ((u >> 16) & 1u)) >> 16;
  return (unsigned short)r;
}

__device__ __forceinline__ f32x4 MF(us8 a, us8 b, f32x4 c) {
  return __builtin_amdgcn_mfma_f32_16x16x32_bf16(
      __builtin_bit_cast(b8, a), __builtin_bit_cast(b8, b), c, 0, 0, 0);
}

// ---------------------------------------------------------------------------
// First conv (CIN=3): scalar-weight version — proven.
// ---------------------------------------------------------------------------
template<int CIN, int COPT, bool RELU, bool RES>
__global__ __launch_bounds__(256) void conv_s_k(
    const float* __restrict__ in, const float* __restrict__ wP,
    const float* __restrict__ bias, const float* __restrict__ res,
    float* __restrict__ out)
{
  const int t   = threadIdx.x;
  const int p   = blockIdx.x * 256 + t;
  const int co0 = blockIdx.y * COPT;
  const int b   = blockIdx.z;
  const int x   = p % WL;
  const bool xl = (x == 0), xr = (x == WL - 1);

  float acc[COPT];
  #pragma unroll
  for (int j = 0; j < COPT; ++j) acc[j] = bias[co0 + j];

  int  ic[3]; bool yv[3];
  int  im[3], ip[3];
  #pragma unroll
  for (int ky = 0; ky < 3; ++ky) {
    int pr = p + (ky - 1) * WL;
    yv[ky] = ((unsigned)pr < (unsigned)PLANE);
    ic[ky] = yv[ky] ? pr : 0;
    im[ky] = ic[ky] - 1; if (im[ky] < 0) im[ky] = 0;
    ip[ky] = ic[ky] + 1; if (ip[ky] > PLANE - 1) ip[ky] = PLANE - 1;
  }

  const float* inb = in + (size_t)b * CIN * PLANE;

  #pragma unroll 2
  for (int ci = 0; ci < CIN; ++ci) {
    const float* pl = inb + (size_t)ci * PLANE;
    #pragma unroll
    for (int ky = 0; ky < 3; ++ky) {
      float am = pl[im[ky]];
      float a0 = pl[ic[ky]];
      float ap = pl[ip[ky]];
      if (!yv[ky]) { am = 0.f; a0 = 0.f; ap = 0.f; }
      if (xl) am = 0.f;
      if (xr) ap = 0.f;
      const float* wrow = wP + (size_t)(ci * 9 + ky * 3) * 64 + co0;
      #pragma unroll
      for (int j = 0; j < COPT; ++j) acc[j] += am * wrow[j];
      #pragma unroll
      for (int j = 0; j < COPT; ++j) acc[j] += a0 * wrow[64 + j];
      #pragma unroll
      for (int j = 0; j < COPT; ++j) acc[j] += ap * wrow[128 + j];
    }
  }

  size_t ob = ((size_t)b * 64 + co0) * PLANE + p;
  #pragma unroll
  for (int j = 0; j < COPT; ++j) {
    float v = acc[j];
    if (RELU) v = fmaxf(v, 0.f);
    if (RES)  v += res[ob + (size_t)j * PLANE];
    out[ob + (size_t)j * PLANE] = v;
  }
}

// ---------------------------------------------------------------------------
// Residual conv (CIN=64): LDS-staged weights (r15-measured best).
// NHWC: final conv writes featT[(b*PLANE+p)*64 + co] directly (transpose
// pass deleted — nothing consumed the final NCHW copy). Acc math identical.
// ---------------------------------------------------------------------------
template<bool RELU, bool RES, bool NHWC>
__global__ __launch_bounds__(256) void conv_lw_k(
    const float* __restrict__ in, const float* __restrict__ wG,
    const float* __restrict__ bias, const float* __restrict__ res,
    float* __restrict__ out)
{
  __shared__ float sw[576 * 4];

  const int t   = threadIdx.x;
  const int p   = blockIdx.x * 256 + t;
  const int co0 = blockIdx.y * 4;
  const int b   = blockIdx.z;
  const int x   = p % WL;
  const bool xl = (x == 0), xr = (x == WL - 1);

  {
    const float4* s4 = (const float4*)(wG + (size_t)blockIdx.y * 2304);
    float4* d4 = (float4*)sw;
    for (int i = t; i < 576; i += 256) d4[i] = s4[i];
  }

  float acc[4];
  #pragma unroll
  for (int j = 0; j < 4; ++j) acc[j] = bias[co0 + j];

  int  ic[3]; bool yv[3];
  int  im[3], ip[3];
  #pragma unroll
  for (int ky = 0; ky < 3; ++ky) {
    int pr = p + (ky - 1) * WL;
    yv[ky] = ((unsigned)pr < (unsigned)PLANE);
    ic[ky] = yv[ky] ? pr : 0;
    im[ky] = ic[ky] - 1; if (im[ky] < 0) im[ky] = 0;
    ip[ky] = ic[ky] + 1; if (ip[ky] > PLANE - 1) ip[ky] = PLANE - 1;
  }

  const float* inb = in + (size_t)b * 64 * PLANE;
  __syncthreads();

  #pragma unroll 2
  for (int ci = 0; ci < 64; ++ci) {
    const float* pl = inb + (size_t)ci * PLANE;
    #pragma unroll
    for (int ky = 0; ky < 3; ++ky) {
      float am = pl[im[ky]];
      float a0 = pl[ic[ky]];
      float ap = pl[ip[ky]];
      if (!yv[ky]) { am = 0.f; a0 = 0.f; ap = 0.f; }
      if (xl) am = 0.f;
      if (xr) ap = 0.f;
      const float* wrow = &sw[(ci * 9 + ky * 3) * 4];
      #pragma unroll
      for (int j = 0; j < 4; ++j) acc[j] += am * wrow[j];
      #pragma unroll
      for (int j = 0; j < 4; ++j) acc[j] += a0 * wrow[4 + j];
      #pragma unroll
      for (int j = 0; j < 4; ++j) acc[j] += ap * wrow[8 + j];
    }
  }

  if (NHWC) {
    size_t ob = ((size_t)b * 64 + co0) * PLANE + p;   // res still NCHW
    float4 v;
    v.x = acc[0]; v.y = acc[1]; v.z = acc[2]; v.w = acc[3];
    if (RELU) {
      v.x = fmaxf(v.x, 0.f); v.y = fmaxf(v.y, 0.f);
      v.z = fmaxf(v.z, 0.f); v.w = fmaxf(v.w, 0.f);
    }
    if (RES) {
      v.x += res[ob];
      v.y += res[ob + (size_t)1 * PLANE];
      v.z += res[ob + (size_t)2 * PLANE];
      v.w += res[ob + (size_t)3 * PLANE];
    }
    *(float4*)(out + ((size_t)b * PLANE + p) * 64 + co0) = v;
  } else {
    size_t ob = ((size_t)b * 64 + co0) * PLANE + p;
    #pragma unroll
    for (int j = 0; j < 4; ++j) {
      float v = acc[j];
      if (RELU) v = fmaxf(v, 0.f);
      if (RES)  v += res[ob + (size_t)j * PLANE];
      out[ob + (size_t)j * PLANE] = v;
    }
  }
}

// ---------------------------------------------------------------------------
// ONE fused prep kernel
// ---------------------------------------------------------------------------
__device__ __forceinline__ void prep_bf16(const float* __restrict__ src,
    unsigned short* __restrict__ dst, int K, int N, int Kp, int i)
{
  int n = i / Kp, k = i - n * Kp;
  float v = (k < K && n < N) ? src[(size_t)k * N + n] : 0.f;
  dst[i] = f2b(v);
}
__device__ __forceinline__ void prep_conv(const float* __restrict__ src,
    float* __restrict__ dst, int cin, int i)
{
  int co = i % 64; int r = i / 64;
  int ci = r / 9, tap = r % 9;
  dst[i] = src[((size_t)co * cin + ci) * 9 + tap];
}
// co-grouped layout for conv_lw_k
__device__ __forceinline__ void prep_conv2(const float* __restrict__ src,
    float* __restrict__ dst, int i)
{
  int j  = i & 3;
  int t2 = i >> 2;
  int cg = t2 / 576;
  int r  = t2 - cg * 576;
  int ci = r / 9, tap = r - ci * 9;
  int co = cg * 4 + j;
  dst[i] = src[((size_t)co * 64 + ci) * 9 + tap];
}

#define PREP_TOTAL 467648
__global__ __launch_bounds__(256) void prep_all_k(
    const float* __restrict__ lw1, const float* __restrict__ lw2,
    const float* __restrict__ lw3, const float* __restrict__ hw1,
    const float* __restrict__ hmw, const float* __restrict__ hwo,
    const float* __restrict__ enc_w_in, const float* __restrict__ enc_rw,
    unsigned short* __restrict__ lw1T, unsigned short* __restrict__ lw2T,
    unsigned short* __restrict__ lw3T, unsigned short* __restrict__ hw1T,
    unsigned short* __restrict__ hm0T, unsigned short* __restrict__ hm1T,
    unsigned short* __restrict__ hwoT, float* __restrict__ cwIn,
    float* __restrict__ cwRes)
{
  int i = blockIdx.x * 256 + threadIdx.x;
  if (i >= PREP_TOTAL) return;
  if (i < 6144)  { prep_bf16(lw1, lw1T, 68, 64, 96, i);    return; } i -= 6144;
  if (i < 4096)  { prep_bf16(lw2, lw2T, 64, 64, 64, i);    return; } i -= 4096;
  if (i < 1024)  { prep_bf16(lw3, lw3T, 64, 3, 64, i);     return; } i -= 1024;
  if (i < 24576) { prep_bf16(hw1, hw1T, 68, 256, 96, i);   return; } i -= 24576;
  if (i < 65536) { prep_bf16(hmw, hm0T, 256, 256, 256, i); return; } i -= 65536;
  if (i < 65536) { prep_bf16(hmw + 65536, hm1T, 256, 256, 256, i); return; } i -= 65536;
  if (i < 4096)  { prep_bf16(hwo, hwoT, 256, 3, 256, i);   return; } i -= 4096;
  if (i < 1728)  { prep_conv(enc_w_in, cwIn, 3, i);        return; } i -= 1728;
  int l = i / 36864, r = i % 36864;
  prep_conv2(enc_rw + (size_t)l * 36864, cwRes + (size_t)l * 36864, r);
}

// ---------------------------------------------------------------------------
// MFMA helpers, parametrized on MT (m-tiles per wave)
// ---------------------------------------------------------------------------
template<int NT, int KT, int MT>
__device__ __forceinline__ void mfma_compute(
    const unsigned short* __restrict__ aBase, int AS,
    const unsigned short* __restrict__ WT, int Kpad,
    int n0, int lane, f32x4 (&acc)[MT][NT])
{
  const int lr = lane & 15;
  const int lc = lane >> 4;
  #pragma unroll
  for (int m = 0; m < MT; ++m)
    #pragma unroll
    for (int j = 0; j < NT; ++j) acc[m][j] = (f32x4){0.f, 0.f, 0.f, 0.f};

  const unsigned short* aP = aBase + lr * AS + lc * 8;
  const unsigned short* bP = WT + (size_t)(n0 + lr) * Kpad + lc * 8;

  constexpr int KCH = (KT >= 4) ? 4 : KT;
  #pragma unroll
  for (int kc = 0; kc < KT; kc += KCH) {
    us8 breg[KCH][NT];
    #pragma unroll
    for (int kk = 0; kk < KCH; ++kk)
      #pragma unroll
      for (int j = 0; j < NT; ++j)
        breg[kk][j] = *(const us8*)(bP + (size_t)j * 16 * Kpad + (kc + kk) * 32);
    #pragma unroll
    for (int kc2 = 0; kc2 < KCH; ++kc2) {
      us8 a0[MT];
      #pragma unroll
      for (int m = 0; m < MT; ++m)
        a0[m] = *(const us8*)(aP + (m * 16) * AS + (kc + kc2) * 32);
      #pragma unroll
      for (int m = 0; m < MT; ++m)
        #pragma unroll
        for (int j = 0; j < NT; ++j)
          acc[m][j] = MF(a0[m], breg[kc2][j], acc[m][j]);
    }
  }
}

template<int NT, bool RELU, int MT>
__device__ __forceinline__ void mfma_store(
    const f32x4 (&acc)[MT][NT], const float* __restrict__ bias,
    unsigned short* __restrict__ dBase, int DS, int dCol0, int n0, int lane)
{
  const int lr = lane & 15;
  const int lc = lane >> 4;
  #pragma unroll
  for (int j = 0; j < NT; ++j) {
    int n = n0 + j * 16 + lr;
    float bv = bias[n];
    #pragma unroll
    for (int m = 0; m < MT; ++m)
      #pragma unroll
      for (int r = 0; r < 4; ++r) {
        float v = acc[m][j][r] + bv;
        if (RELU) v = fmaxf(v, 0.f);
        dBase[(m * 16 + lc * 4 + r) * DS + dCol0 + n] = f2b(v);
      }
  }
}

template<int KT>
__device__ __forceinline__ void mfma_out3w(
    const unsigned short* __restrict__ aBase, int AS,
    const unsigned short* __restrict__ WT, int Kpad,
    const float* __restrict__ bias, float (*dst)[4], int mtile, int lane)
{
  const int lr = lane & 15;
  const int lc = lane >> 4;
  f32x4 acc = (f32x4){0.f, 0.f, 0.f, 0.f};
  const unsigned short* aP = aBase + (mtile * 16 + lr) * AS + lc * 8;
  const unsigned short* bP = WT + (size_t)lr * Kpad + lc * 8;

  constexpr int KCH = (KT >= 4) ? 4 : KT;
  #pragma unroll
  for (int kc = 0; kc < KT; kc += KCH) {
    us8 breg[KCH];
    #pragma unroll
    for (int kk = 0; kk < KCH; ++kk)
      breg[kk] = *(const us8*)(bP + (kc + kk) * 32);
    #pragma unroll
    for (int kk = 0; kk < KCH; ++kk) {
      us8 a = *(const us8*)(aP + (kc + kk) * 32);
      acc = MF(a, breg[kk], acc);
    }
  }
  if (lr < 3) {
    float bv = bias[lr];
    #pragma unroll
    for (int r = 0; r < 4; ++r)
      dst[mtile * 16 + lc * 4 + r][lr] = acc[r] + bv;
  }
}

// ---------------------------------------------------------------------------
// Shared helpers
// ---------------------------------------------------------------------------
__device__ __forceinline__ void nearest_idx(float gy, float gx, int& iy, int& ix)
{
  float fy = (gy + 1.f) * (HL * 0.5f) - 0.5f;
  float fx = (gx + 1.f) * (WL * 0.5f) - 0.5f;
  iy = min(max((int)floorf(fy + 0.5f), 0), HL - 1);
  ix = min(max((int)floorf(fx + 0.5f), 0), WL - 1);
}

__device__ __forceinline__ float bilinear_lr(const float* __restrict__ lrimg,
                                             int b, int ch, float gy, float gx)
{
  float x = (gx + 1.f) * (WL * 0.5f) - 0.5f;
  float y = (gy + 1.f) * (HL * 0.5f) - 0.5f;
  float xf = floorf(x), yf = floorf(y);
  float wx = x - xf, wy = y - yf;
  int x0i = min(max((int)xf,     0), WL - 1);
  int x1i = min(max((int)xf + 1, 0), WL - 1);
  int y0i = min(max((int)yf,     0), HL - 1);
  int y1i = min(max((int)yf + 1, 0), HL - 1);
  const float* img = lrimg + ((size_t)b * 3 + ch) * PLANE;
  float v00 = img[y0i * WL + x0i], v01 = img[y0i * WL + x1i];
  float v10 = img[y1i * WL + x0i], v11 = img[y1i * WL + x1i];
  return v00 * (1.f - wx) * (1.f - wy) + v01 * wx * (1.f - wy)
       + v10 * (1.f - wx) * wy + v11 * wx * wy;
}

// ---------------------------------------------------------------------------
// Pass 1 (v5, r14/r22 proven): scalar-weight classifier, 2 px/thread.
// FROZEN: LDS-weights (r20) and 4px/thread (r23) both spilled to scratch.
// ---------------------------------------------------------------------------
template<int JB>
__device__ __forceinline__ void cls_block2(
    const float* __restrict__ fpA, const float* __restrict__ fpB,
    const float4& eA, const float4& eB,
    const float* __restrict__ cw1, const float* __restrict__ cb1,
    const float* __restrict__ cw2, int j0,
    float& l0a, float& l1a, float& l0b, float& l1b)
{
  float accA[JB], accB[JB];
  #pragma unroll
  for (int j = 0; j < JB; ++j) { accA[j] = cb1[j0 + j]; accB[j] = accA[j]; }
  #pragma unroll 4
  for (int kq = 0; kq < 16; ++kq) {
    float4 a4A = *(const float4*)(fpA + kq * 4);
    float4 a4B = *(const float4*)(fpB + kq * 4);
    float avA[4] = {a4A.x, a4A.y, a4A.z, a4A.w};
    float avB[4] = {a4B.x, a4B.y, a4B.z, a4B.w};
    #pragma unroll
    for (int kk = 0; kk < 4; ++kk) {
      const float* wr = cw1 + (size_t)(kq * 4 + kk) * 64 + j0;
      float aA = avA[kk], aB = avB[kk];
      #pragma unroll
      for (int j = 0; j < JB; ++j) { accA[j] += aA * wr[j]; accB[j] += aB * wr[j]; }
    }
  }
  {
    const float* wr = cw1 + (size_t)64 * 64 + j0;
    #pragma unroll
    for (int j = 0; j < JB; ++j) { accA[j] += eA.x * wr[j]; accB[j] += eB.x * wr[j]; }
    wr += 64;
    #pragma unroll
    for (int j = 0; j < JB; ++j) { accA[j] += eA.y * wr[j]; accB[j] += eB.y * wr[j]; }
    wr += 64;
    #pragma unroll
    for (int j = 0; j < JB; ++j) { accA[j] += eA.z * wr[j]; accB[j] += eB.z * wr[j]; }
    wr += 64;
    #pragma unroll
    for (int j = 0; j < JB; ++j) { accA[j] += eA.w * wr[j]; accB[j] += eB.w * wr[j]; }
  }
  #pragma unroll
  for (int j = 0; j < JB; ++j) {
    float hA = fmaxf(accA[j], 0.f);
    float hB = fmaxf(accB[j], 0.f);
    float w0 = cw2[(j0 + j) * 2 + 0], w1 = cw2[(j0 + j) * 2 + 1];
    l0a += hA * w0; l1a += hA * w1;
    l0b += hB * w0; l1b += hB * w1;
  }
}

__global__ __launch_bounds__(256, 4) void cls_gate2_k(
    const float* __restrict__ featT, const float* __restrict__ coord,
    const float* __restrict__ cell,
    const float* __restrict__ cw1, const float* __restrict__ cb1,
    const float* __restrict__ cw2, const float* __restrict__ cb2,
    int* __restrict__ counters, unsigned* __restrict__ easyList,
    unsigned* __restrict__ hardList)
{
  const int T  = blockIdx.x * 256 + threadIdx.x;
  const int gA = T * 2, gB = gA + 1;

  int bA = gA / (HO * WO);
  float gyA = coord[(size_t)gA * 2 + 0];
  float gxA = coord[(size_t)gA * 2 + 1];
  int iyA, ixA; nearest_idx(gyA, gxA, iyA, ixA);
  const float* fpA = featT + (((size_t)bA * PLANE) + iyA * WL + ixA) * 64;
  float4 eA;
  { float cy = (2.f * iyA + 1.f) / HL - 1.f;
    float cx = (2.f * ixA + 1.f) / WL - 1.f;
    eA.x = (gyA - cy) * HL; eA.y = (gxA - cx) * WL;
    eA.z = cell[(size_t)gA * 2 + 0] * HL; eA.w = cell[(size_t)gA * 2 + 1] * WL; }

  int bB = gB / (HO * WO);
  float gyB = coord[(size_t)gB * 2 + 0];
  float gxB = coord[(size_t)gB * 2 + 1];
  int iyB, ixB; nearest_idx(gyB, gxB, iyB, ixB);
  const float* fpB = featT + (((size_t)bB * PLANE) + iyB * WL + ixB) * 64;
  float4 eB;
  { float cy = (2.f * iyB + 1.f) / HL - 1.f;
    float cx = (2.f * ixB + 1.f) / WL - 1.f;
    eB.x = (gyB - cy) * HL; eB.y = (gxB - cx) * WL;
    eB.z = cell[(size_t)gB * 2 + 0] * HL; eB.w = cell[(size_t)gB * 2 + 1] * WL; }

  float l0a = cb2[0], l1a = cb2[1];
  float l0b = cb2[0], l1b = cb2[1];
  cls_block2<32>(fpA, fpB, eA, eB, cw1, cb1, cw2, 0,  l0a, l1a, l0b, l1b);
  cls_block2<32>(fpA, fpB, eA, eB, cw1, cb1, cw2, 32, l0a, l1a, l0b, l1b);
  bool hardA = (l1a > l0a);
  bool hardB = (l1b > l0b);

  unsigned long long mh0 = __ballot(hardA);
  unsigned long long mh1 = __ballot(hardB);
  int lane = threadIdx.x & 63;
  int nh0 = __popcll(mh0), nh1 = __popcll(mh1);
  int nh = nh0 + nh1;
  int baseH = 0, baseE = 0;
  if (lane == 0) {
    baseH = atomicAdd(&counters[1], nh);
    baseE = atomicAdd(&counters[0], 128 - nh);
  }
  baseH = __shfl(baseH, 0);
  baseE = __shfl(baseE, 0);
  unsigned long long below = (1ull << lane) - 1ull;
  int hbA = __popcll(mh0 & below);
  int hbB = nh0 + __popcll(mh1 & below);
  int ebA = lane - hbA;
  int ebB = (64 - nh0) + (lane - __popcll(mh1 & below));
  if (hardA) hardList[baseH + hbA] = (unsigned)gA;
  else       easyList[baseE + ebA] = (unsigned)gA;
  if (hardB) hardList[baseH + hbB] = (unsigned)gB;
  else       easyList[baseE + ebB] = (unsigned)gB;
}

// ---------------------------------------------------------------------------
// Gather helper (raw pointer, stride 104)
// ---------------------------------------------------------------------------
__device__ __forceinline__ void build_inp_row(
    const float* __restrict__ featT, const float* __restrict__ coord,
    const float* __restrict__ cell, unsigned g, int p, int q8,
    unsigned short* __restrict__ sInpB)  // [*][104]
{
  int b = g / (HO * WO);
  float gy = coord[(size_t)g * 2 + 0];
  float gx = coord[(size_t)g * 2 + 1];
  int iy, ix; nearest_idx(gy, gx, iy, ix);
  const float* fpt = featT + (((size_t)b * PLANE) + iy * WL + ix) * 64 + q8 * 8;
  float4 u0 = *(const float4*)fpt;
  float4 u1 = *(const float4*)(fpt + 4);
  us8 pk;
  pk[0]=f2b(u0.x); pk[1]=f2b(u0.y); pk[2]=f2b(u0.z); pk[3]=f2b(u0.w);
  pk[4]=f2b(u1.x); pk[5]=f2b(u1.y); pk[6]=f2b(u1.z); pk[7]=f2b(u1.w);
  *(us8*)&sInpB[p * 104 + q8 * 8] = pk;
  if (q8 == 0) {
    float cy = (2.f * iy + 1.f) / HL - 1.f;
    float cx = (2.f * ix + 1.f) / WL - 1.f;
    float e0 = (gy - cy) * HL, e1 = (gx - cx) * WL;
    float e2 = cell[(size_t)g * 2 + 0] * HL, e3 = cell[(size_t)g * 2 + 1] * WL;
    us4 pe; pe[0]=f2b(e0); pe[1]=f2b(e1); pe[2]=f2b(e2); pe[3]=f2b(e3);
    *(us4*)&sInpB[p * 104 + 64] = pe;
  }
  if (q8 == 1) {
    us4 z = (us4){0,0,0,0};
    #pragma unroll
    for (int c = 0; c < 9; ++c) *(us4*)&sInpB[p * 104 + 68 + c * 4] = z;
  }
}

// ---------------------------------------------------------------------------
// Merged heavy+light, dynamic LDS (~70KB) — r22 proven.
// ---------------------------------------------------------------------------
#define HLDS (128*264*2 + 128*4*4 + 128*4)   // 70144 B

__global__ __launch_bounds__(512, 2) void ml2_k(
    const float* __restrict__ featT, const float* __restrict__ coord,
    const float* __restrict__ cell,  const float* __restrict__ lrimg,
    const float* __restrict__ lb1, const float* __restrict__ lb2,
    const float* __restrict__ lb3,
    const unsigned short* __restrict__ lw1T, const unsigned short* __restrict__ lw2T,
    const unsigned short* __restrict__ lw3T,
    const float* __restrict__ hb1, const float* __restrict__ hmb,
    const float* __restrict__ hbo,
    const unsigned short* __restrict__ hw1T, const unsigned short* __restrict__ hm0T,
    const unsigned short* __restrict__ hm1T, const unsigned short* __restrict__ hwoT,
    const int* __restrict__ counters,
    const unsigned* __restrict__ easyList, const unsigned* __restrict__ hardList,
    float* __restrict__ out)
{
  extern __shared__ char smem[];
  const int t = threadIdx.x, lane = t & 63, w = t >> 6;

  if (blockIdx.x < HG2) {
    unsigned short* sBuf = (unsigned short*)smem;
    float (*sP)[4]       = (float (*)[4])(smem + 128*264*2);
    unsigned* sIdx       = (unsigned*)(smem + 128*264*2 + 128*16);

    const int nH = counters[1];
    const int g0 = blockIdx.x * 128;
    if (g0 >= nH) return;

    {
      const int p = t >> 2, q = t & 3;
      int i = g0 + p; if (i > nH - 1) i = nH - 1;
      unsigned g = hardList[i];
      if (q == 0) sIdx[p] = g;
      build_inp_row(featT, coord, cell, g, p, q * 2,     sBuf);
      build_inp_row(featT, coord, cell, g, p, q * 2 + 1, sBuf);
    }
    __syncthreads();

    { f32x4 acc[8][2];
      mfma_compute<2, 3, 8>(sBuf, 104, hw1T, 96, w * 32, lane, acc);
      __syncthreads();
      mfma_store<2, true, 8>(acc, hb1, sBuf, 264, 0, w * 32, lane); }
    __syncthreads();
    { f32x4 acc[8][2];
      mfma_compute<2, 8, 8>(sBuf, 264, hm0T, 256, w * 32, lane, acc);
      __syncthreads();
      mfma_store<2, true, 8>(acc, hmb, sBuf, 264, 0, w * 32, lane); }
    __syncthreads();
    { f32x4 acc[8][2];
      mfma_compute<2, 8, 8>(sBuf, 264, hm1T, 256, w * 32, lane, acc);
      __syncthreads();
      mfma_store<2, true, 8>(acc, hmb + 256, sBuf, 264, 0, w * 32, lane); }
    __syncthreads();
    mfma_out3w<8>(sBuf, 264, hwoT, 256, hbo, sP, w, lane);
    __syncthreads();

    if (t < 384) {
      int p = t / 3, ch = t % 3;
      int i = g0 + p;
      if (i < nH) {
        unsigned g = sIdx[p];
        int b = g / (HO * WO);
        int rem = g % (HO * WO);
        int oy = rem / WO, ox = rem % WO;
        float gy = coord[(size_t)g * 2 + 0];
        float gx = coord[(size_t)g * 2 + 1];
        float v = bilinear_lr(lrimg, b, ch, gy, gx);
        out[(((size_t)b * 3 + ch) * HO + oy) * WO + ox] = sP[p][ch] + v;
      }
    }
  } else {
    unsigned short* sInpB = (unsigned short*)smem;              // 64*104
    unsigned short* sL1   = (unsigned short*)(smem + 13312);    // 64*72
    unsigned short* sL2   = (unsigned short*)(smem + 13312 + 9216);
    float (*sP)[4]        = (float (*)[4])(smem + 13312 + 2*9216);
    unsigned* sIdx        = (unsigned*)(smem + 13312 + 2*9216 + 1024);

    const int nE = counters[0];
    const int g0 = (blockIdx.x - HG2) * 64;
    if (g0 >= nE) return;

    if (t < 256) {
      const int p = t >> 2, q = t & 3;
      int i = g0 + p; if (i > nE - 1) i = nE - 1;
      unsigned g = easyList[i];
      if (q == 0) sIdx[p] = g;
      build_inp_row(featT, coord, cell, g, p, q * 2,     sInpB);
      build_inp_row(featT, coord, cell, g, p, q * 2 + 1, sInpB);
    }
    __syncthreads();

    if (w < 4) {
      f32x4 acc[4][1];
      mfma_compute<1, 3, 4>(sInpB, 104, lw1T, 96, w * 16, lane, acc);
      mfma_store<1, true, 4>(acc, lb1, sL1, 72, 0, w * 16, lane);
    }
    __syncthreads();
    if (w < 4) {
      f32x4 acc[4][1];
      mfma_compute<1, 2, 4>(sL1, 72, lw2T, 64, w * 16, lane, acc);
      mfma_store<1, true, 4>(acc, lb2, sL2, 72, 0, w * 16, lane);
    }
    __syncthreads();
    if (w < 4) mfma_out3w<2>(sL2, 72, lw3T, 64, lb3, sP, w, lane);
    __syncthreads();

    if (t < 192) {
      int p = t / 3, ch = t % 3;
      int i = g0 + p;
      if (i < nE) {
        unsigned g = sIdx[p];
        int b = g / (HO * WO);
        int rem = g % (HO * WO);
        int oy = rem / WO, ox = rem % WO;
        float gy = coord[(size_t)g * 2 + 0];
        float gx = coord[(size_t)g * 2 + 1];
        float v = bilinear_lr(lrimg, b, ch, gy, gx);
        out[(((size_t)b * 3 + ch) * HO + oy) * WO + ox] = sP[p][ch] + v;
      }
    }
  }
}

__global__ void finalize_k(const int* __restrict__ counters, float* __restrict__ out)
{
  out[(size_t)NPIX * 3] = (float)(counters[0]) / (float)NPIX;
}

// ---------------------------------------------------------------------------
extern "C" void kernel_launch(void* const* d_in, const int* in_sizes, int n_in,
                              void* d_out, int out_size, void* d_ws, size_t ws_size,
                              hipStream_t stream)
{
  const float* lr       = (const float*)d_in[0];
  const float* coord    = (const float*)d_in[1];
  const float* cell     = (const float*)d_in[2];
  const float* enc_w_in = (const float*)d_in[3];
  const float* enc_b_in = (const float*)d_in[4];
  const float* enc_rw   = (const float*)d_in[5];
  const float* enc_rb   = (const float*)d_in[6];
  const float* cw1      = (const float*)d_in[7];
  const float* cb1      = (const float*)d_in[8];
  const float* cw2      = (const float*)d_in[9];
  const float* cb2      = (const float*)d_in[10];
  const float* lw1      = (const float*)d_in[11];
  const float* lb1      = (const float*)d_in[12];
  const float* lw2      = (const float*)d_in[13];
  const float* lb2      = (const float*)d_in[14];
  const float* lw3      = (const float*)d_in[15];
  const float* lb3      = (const float*)d_in[16];
  const float* hw1      = (const float*)d_in[17];
  const float* hb1      = (const float*)d_in[18];
  const float* hmw      = (const float*)d_in[19];
  const float* hmb      = (const float*)d_in[20];
  const float* hwo      = (const float*)d_in[21];
  const float* hbo      = (const float*)d_in[22];
  float* out = (float*)d_out;

  char* ws = (char*)d_ws;
  float* xA    = (float*)(ws + 1024);
  float* tmp   = xA  + FEAT_ELEMS;
  float* xB    = tmp + FEAT_ELEMS;
  float* featT = tmp;                 // NHWC feat written by final conv
  unsigned short* wb = (unsigned short*)(xB + FEAT_ELEMS);
  unsigned short* lw1T = wb;              // 64*96
  unsigned short* lw2T = lw1T + 64*96;    // 64*64
  unsigned short* lw3T = lw2T + 64*64;    // 16*64
  unsigned short* hw1T = lw3T + 16*64;    // 256*96
  unsigned short* hm0T = hw1T + 256*96;   // 256*256
  unsigned short* hm1T = hm0T + 65536;    // 256*256
  unsigned short* hwoT = hm1T + 65536;    // 16*256
  const size_t nb16 = 64*96 + 64*64 + 16*64 + 256*96 + 2*65536 + 16*256; // 171008
  float* cwIn  = (float*)(wb + nb16);     // 27*64 = 1728
  float* cwRes = cwIn + 1728;             // 8 * 36864 (co-grouped layout)
  size_t need = 1024 + 3 * FEAT_ELEMS * sizeof(float)
              + nb16 * 2 + (1728 + 8 * 36864) * sizeof(float);
  if (ws_size < need) return;

  int*      counters = (int*)xB;
  unsigned* easyList = (unsigned*)(xB + 16);
  unsigned* hardList = easyList + NPIX;

  // allow >64KB dynamic LDS for the merged kernel
  hipFuncSetAttribute((const void*)ml2_k,
                      hipFuncAttributeMaxDynamicSharedMemorySize, HLDS);

  prep_all_k<<<(PREP_TOTAL + 255) / 256, 256, 0, stream>>>(
      lw1, lw2, lw3, hw1, hmw, hwo, enc_w_in, enc_rw,
      lw1T, lw2T, lw3T, hw1T, hm0T, hm1T, hwoT, cwIn, cwRes);

  // --- encoder (fp32; LDS-weight residual convs) ---
  // Layer chain: conv1 -> xA; for i<3: (cur->tmp->oth NCHW, swap);
  // final block (i==3): conv->tmp (NCHW), then RES-conv writes featT (NHWC).
  dim3 cgrid(36, 16, 2);
  conv_s_k<3, 4, false, false><<<cgrid, 256, 0, stream>>>(lr, cwIn, enc_b_in, nullptr, xA);

  float* cur = xA; float* oth = xB;
  for (int i = 0; i < 3; ++i) {
    const float* wp0 = cwRes + (size_t)(2 * i)     * 36864;
    const float* wp1 = cwRes + (size_t)(2 * i + 1) * 36864;
    const float* b0 = enc_rb + i * 128;
    const float* b1 = b0 + 64;
    conv_lw_k<true,  false, false><<<cgrid, 256, 0, stream>>>(cur, wp0, b0, nullptr, tmp);
    conv_lw_k<false, true,  false><<<cgrid, 256, 0, stream>>>(tmp, wp1, b1, cur, oth);
    float* sw2p = cur; cur = oth; oth = sw2p;
  }
  // after 3 swaps: cur == xB, oth == xA.  Final block: use oth(=xA) as scratch
  // is NOT free (cur holds live feat)... tmp is free. Write mid to oth? oth==xA
  // free (old data consumed). Use: conv->tmp would clobber?? tmp holds nothing
  // live now (featT not yet written). mid -> oth(xA), final NHWC -> featT(tmp).
  {
    const float* wp0 = cwRes + (size_t)6 * 36864;
    const float* wp1 = cwRes + (size_t)7 * 36864;
    const float* b0 = enc_rb + 3 * 128;
    const float* b1 = b0 + 64;
    conv_lw_k<true,  false, false><<<cgrid, 256, 0, stream>>>(cur, wp0, b0, nullptr, oth);
    conv_lw_k<false, true,  true ><<<cgrid, 256, 0, stream>>>(oth, wp1, b1, cur, featT);
  }
  // cur == xB still holds pre-final feat (dead now) -> xB free for lists AFTER
  // the final convs complete (same-stream ordering guarantees this).

  hipMemsetAsync(counters, 0, 16, stream);

  cls_gate2_k<<<NPIX / 512, 256, 0, stream>>>(featT, coord, cell,
      cw1, cb1, cw2, cb2, counters, easyList, hardList);

  ml2_k<<<HG2 + LG2, 512, HLDS, stream>>>(featT, coord, cell, lr,
      lb1, lb2, lb3, lw1T, lw2T, lw3T,
      hb1, hmb, hbo, hw1T, hm0T, hm1T, hwoT,
      counters, easyList, hardList, out);

  finalize_k<<<1, 1, 0, stream>>>(counters, out);
}